// Round 4
// baseline (316.586 us; speedup 1.0000x reference)
//
#include <hip/hip_runtime.h>
#include <math.h>

// ---------------------------------------------------------------------------
// MultiChannelAttention on MI355X (gfx950)
// out = softmax(causal(rope(xWq^T) rope(xWk^T)^T / sqrt(C))) (xWv^T) Wf^T + b
// B=4 T=2048 C=1024. bf16 MFMA (16x16x32), fp32 accum.
// R12: proj_rope -> core256: 256x256 block tile, 8 waves of 128x64
//      (acc[8][4], FLOP/LDS-byte 32 -> 43.7, MFMA-per-barrier 2x). Same
//      verified pipeline skeleton as core4 (3 K-tiles prefetch in flight,
//      vmcnt(12) certify, 2 barriers/K-tile, chunk-swizzled LDS). Single
//      384-block fused grid (Q/K/V), XCD-chunked remap. R11 core4 kept for
//      final_gemm. Theory: R9-R11 all hit 27% MfmaUtil = LDS-read-BW bound
//      at 64x64 wave tiles; bigger wave tile is the m198->m201 lever.
// R11: core4 software pipeline (reg-dbuf fragments, counted vmcnt).
// R8: V projection computes Vt natively (A=Wv, B=x). R7: triangular score
//     grid; pv longest-K-first. R5: native v_sin/v_cos RoPE. R2: fused
//     exp-softmax (P=exp(s) bf16 + atomic row sums).
// Workspace layout (121 MB):
//   [0,16) xb  [16,24) Wq/Wk/Wv/Wf bf16  [24,40) Q  [40,56) K
//   [56,72) Vt  [72,88) O  [88,120) P bf16  [120,+32K) row_sum
// ---------------------------------------------------------------------------

#define AS1(p) ((__attribute__((address_space(1))) void*)(p))
#define AS3(p) ((__attribute__((address_space(3))) void*)(p))

typedef __attribute__((ext_vector_type(8))) short bf16x8;
typedef __attribute__((ext_vector_type(4))) float f32x4;

__device__ __forceinline__ unsigned short f2bf(float f) {
  unsigned int u = __float_as_uint(f);
  u += 0x7fffu + ((u >> 16) & 1u);   // round-to-nearest-even
  return (unsigned short)(u >> 16);
}

// ---- fp32 -> bf16 cast for x + 4 weight matrices, one launch --------------
__global__ __launch_bounds__(256) void cast_all(
    const float* __restrict__ x, const float* __restrict__ Wq,
    const float* __restrict__ Wk, const float* __restrict__ Wv,
    const float* __restrict__ Wf,
    unsigned short* __restrict__ xb, unsigned short* __restrict__ Wqb,
    unsigned short* __restrict__ Wkb, unsigned short* __restrict__ Wvb,
    unsigned short* __restrict__ Wfb) {
  int i = blockIdx.x * 256 + threadIdx.x;           // float4 index
  const float* src; unsigned short* dst; int off;
  if (i < 2097152) { src = x; dst = xb; off = i; }
  else {
    int j = i - 2097152;
    int w = j >> 18; off = j & 262143;              // 262144 float4 per W
    src = (w == 0) ? Wq : (w == 1) ? Wk : (w == 2) ? Wv : Wf;
    dst = (w == 0) ? Wqb : (w == 1) ? Wkb : (w == 2) ? Wvb : Wfb;
  }
  float4 f = ((const float4*)src)[off];
  ushort4 o;
  o.x = f2bf(f.x); o.y = f2bf(f.y); o.z = f2bf(f.z); o.w = f2bf(f.w);
  ((ushort4*)dst)[off] = o;
}

// ---- legacy 128x128 bt-GEMM core (256 thr), used by score_exp / pv_gemm ---
__device__ __forceinline__ void gemm_core(const unsigned short* __restrict__ At, long long lda,
                                          const unsigned short* __restrict__ Bt, long long ldb,
                                          int K, f32x4 (&acc)[4][4],
                                          unsigned short* As, unsigned short* Bs) {
  const int tid  = threadIdx.x;
  const int lane = tid & 63;
  const int w    = tid >> 6;
  const int wm   = (w & 1) << 6;
  const int wn   = (w >> 1) << 6;
  const int fr   = lane & 15;
  const int fq   = lane >> 4;
  const int srow = tid >> 2;
  const int scol = (tid & 3) << 3;
  const int lg   = ((tid & 3) ^ ((srow >> 1) & 3)) << 3;
  const unsigned short* a0 = At + (long long)srow * lda + lg;
  const unsigned short* a1 = At + (long long)(srow + 64) * lda + lg;
  const unsigned short* b0 = Bt + (long long)srow * ldb + lg;
  const unsigned short* b1 = Bt + (long long)(srow + 64) * ldb + lg;
  unsigned short* As0 = As + srow * 32 + scol;
  unsigned short* As1 = As + (srow + 64) * 32 + scol;
  unsigned short* Bs0 = Bs + srow * 32 + scol;
  unsigned short* Bs1 = Bs + (srow + 64) * 32 + scol;
  const int pg = (fq ^ ((fr >> 1) & 3)) << 3;
  for (int k0 = 0; k0 < K; k0 += 32) {
    __builtin_amdgcn_global_load_lds(AS1(a0 + k0), AS3(As0), 16, 0, 0);
    __builtin_amdgcn_global_load_lds(AS1(a1 + k0), AS3(As1), 16, 0, 0);
    __builtin_amdgcn_global_load_lds(AS1(b0 + k0), AS3(Bs0), 16, 0, 0);
    __builtin_amdgcn_global_load_lds(AS1(b1 + k0), AS3(Bs1), 16, 0, 0);
    __syncthreads();
    bf16x8 af[4], bfr[4];
#pragma unroll
    for (int i = 0; i < 4; i++)
      af[i] = *(const bf16x8*)(As + (wm + i * 16 + fr) * 32 + pg);
#pragma unroll
    for (int i = 0; i < 4; i++)
      bfr[i] = *(const bf16x8*)(Bs + (wn + i * 16 + fr) * 32 + pg);
#pragma unroll
    for (int mi = 0; mi < 4; mi++)
#pragma unroll
      for (int ni = 0; ni < 4; ni++)
        acc[mi][ni] = __builtin_amdgcn_mfma_f32_16x16x32_bf16(af[mi], bfr[ni], acc[mi][ni], 0, 0, 0);
    __syncthreads();
  }
}

// ---- LDS repack + coalesced bf16x8 store of one mi-slice (legacy) ---------
__device__ __forceinline__ void repack_store_mi(unsigned short (&vals)[4][4],
                                                unsigned short* sh, int mi,
                                                int m0, int n0, long long ldo,
                                                unsigned short* __restrict__ Out) {
  const int tid = threadIdx.x, lane = tid & 63, w = tid >> 6;
  const int half = w & 1, wn = (w >> 1) << 6;
  const int cl = lane & 15, q4 = lane >> 4;
  const int lr = half * 16 + q4 * 4;
#pragma unroll
  for (int ni = 0; ni < 4; ni++)
#pragma unroll
    for (int rr = 0; rr < 4; rr++)
      sh[(lr + rr) * 132 + wn + ni * 16 + cl] = vals[ni][rr];
  __syncthreads();
#pragma unroll
  for (int it = 0; it < 2; ++it) {
    int row = (tid >> 4) + it * 16;          // 0..31
    int c8 = (tid & 15) << 3;                // 0..120
    bf16x8 v = *(const bf16x8*)(sh + row * 132 + c8);
    int gr = m0 + (row < 16 ? mi * 16 + row : 48 + mi * 16 + row);
    *(bf16x8*)(Out + (long long)gr * ldo + n0 + c8) = v;
  }
  __syncthreads();
}

// ---------------------------------------------------------------------------
// core4 (kept for final_gemm): 128x256 tile, per-wave 64x64, BK=32, 4 LDS
// buffers (48 KiB), 3-deep prefetch, reg-dbuf fragments. See R11 notes.
// ---------------------------------------------------------------------------
__device__ __forceinline__ void core4(
    const unsigned short* __restrict__ A, long long lda,
    const unsigned short* __restrict__ B, long long ldb,
    int nkt, f32x4 (&acc)[4][4], unsigned short* lds) {
  const int tid  = threadIdx.x;
  const int lane = tid & 63;
  const int w    = tid >> 6;
  const int wr   = w >> 2;            // 0..1
  const int wc   = w & 3;             // 0..3
  const int fr   = lane & 15;
  const int fq   = lane >> 4;
  const int csel = (fq ^ ((fr >> 1) & 3)) << 3;   // fragment chunk swizzle
  const int srow = tid >> 2;                      // staging row 0..127
  const int scsw = ((tid & 3) ^ ((srow >> 1) & 3)) << 3;
  const unsigned short* Asrc  = A + (long long)srow * lda + scsw;
  const unsigned short* Bsrc0 = B + (long long)srow * ldb + scsw;
  const unsigned short* Bsrc1 = B + (long long)(srow + 128) * ldb + scsw;
  unsigned short* dsta = lds + tid * 8;           // per-thread 16B slot

  auto stage = [&](int kt) {
    const int bo = (kt & 3) * 12288;
    const long long ko = (long long)kt * 32;
    __builtin_amdgcn_global_load_lds(AS1(Asrc + ko),  AS3(dsta + bo),        16, 0, 0);
    __builtin_amdgcn_global_load_lds(AS1(Bsrc0 + ko), AS3(dsta + bo + 4096), 16, 0, 0);
    __builtin_amdgcn_global_load_lds(AS1(Bsrc1 + ko), AS3(dsta + bo + 8192), 16, 0, 0);
  };
  auto rdfrag = [&](int kt, bf16x8 (&r)[8]) {
    const unsigned short* Ab = lds + (kt & 3) * 12288 + (wr * 64 + fr) * 32 + csel;
    const unsigned short* Bb = lds + (kt & 3) * 12288 + 4096 + (wc * 64 + fr) * 32 + csel;
#pragma unroll
    for (int mi = 0; mi < 4; ++mi) r[mi] = *(const bf16x8*)(Ab + mi * 512);
#pragma unroll
    for (int nj = 0; nj < 4; ++nj) r[4 + nj] = *(const bf16x8*)(Bb + nj * 512);
  };

  bf16x8 ra[8], rb[8];
  stage(0); stage(1); stage(2);
  asm volatile("s_waitcnt vmcnt(6)" ::: "memory");
  __builtin_amdgcn_s_barrier();
  rdfrag(0, ra);

  auto body = [&](int kt, bf16x8 (&cur)[8], bf16x8 (&nxt)[8]) {
    if (kt + 3 < nkt) {
      stage(kt + 3);
      asm volatile("s_waitcnt vmcnt(6)" ::: "memory");
    } else if (kt + 2 < nkt) {
      asm volatile("s_waitcnt vmcnt(3)" ::: "memory");
    } else if (kt + 1 < nkt) {
      asm volatile("s_waitcnt vmcnt(0)" ::: "memory");
    }
    if (kt + 1 < nkt) {
      __builtin_amdgcn_s_barrier();
      rdfrag(kt + 1, nxt);
    }
    __builtin_amdgcn_s_setprio(1);
#pragma unroll
    for (int mi = 0; mi < 4; ++mi)
#pragma unroll
      for (int nj = 0; nj < 4; ++nj)
        acc[mi][nj] = __builtin_amdgcn_mfma_f32_16x16x32_bf16(cur[mi], cur[4 + nj], acc[mi][nj], 0, 0, 0);
    __builtin_amdgcn_s_setprio(0);
    if (kt + 1 < nkt) __builtin_amdgcn_s_barrier();
  };

#pragma unroll 1
  for (int kt = 0; kt < nkt; kt += 2) {
    body(kt, ra, rb);
    body(kt + 1, rb, ra);
  }
}

// ---------------------------------------------------------------------------
// core256: 256x256 block tile, 512 thr = 8 waves (2M x 4N), per-wave 128x64
// (acc[8][4]). BK=32; 4 LDS buffers of 32 KiB = 128 KiB total:
//   buf kt&3 at (kt&3)*16384 shorts: A[256][32] at +0, B[256][32] at +8192.
// 16B chunks swizzled c ^= (row>>1)&3 (pre-swizzled GLOBAL source, linear
// LDS dest; sel = fq ^ ((fr>>1)&3) on reads -- row-independent, 2-way banks).
// Pipeline: 3 K-tiles of prefetch in flight (12 loads), vmcnt(12) certifies
// the current tile; fragments read IN-body (all consumed before the trailing
// barrier, so no outstanding ds_read crosses the WAR point). 2 barriers and
// 32 MFMA per wave per K-tile. C[m,n] = sum_k A[m,k]*B[n,k]. nkt >= 4.
// ---------------------------------------------------------------------------
__device__ __forceinline__ void core256(
    const unsigned short* __restrict__ A, long long lda,
    const unsigned short* __restrict__ B, long long ldb,
    int nkt, f32x4 (&acc)[8][4], unsigned short* lds) {
  const int tid  = threadIdx.x;
  const int lane = tid & 63;
  const int w    = tid >> 6;
  const int wr   = w >> 2;            // 0..1  (M half: rows wr*128..+128)
  const int wc   = w & 3;             // 0..3  (N quarter: cols wc*64..+64)
  const int fr   = lane & 15;
  const int fq   = lane >> 4;
  const int csel = (fq ^ ((fr >> 1) & 3)) << 3;
  const int srow = tid >> 2;          // 0..127
  const int scsw = ((tid & 3) ^ ((srow >> 1) & 3)) << 3;
  const unsigned short* As0 = A + (long long)srow * lda + scsw;
  const unsigned short* As1 = A + (long long)(srow + 128) * lda + scsw;
  const unsigned short* Bs0 = B + (long long)srow * ldb + scsw;
  const unsigned short* Bs1 = B + (long long)(srow + 128) * ldb + scsw;
  unsigned short* dsta = lds + tid * 8;

  auto stage = [&](int kt) {
    const int bo = (kt & 3) * 16384;
    const long long ko = (long long)kt * 32;
    __builtin_amdgcn_global_load_lds(AS1(As0 + ko), AS3(dsta + bo),         16, 0, 0);
    __builtin_amdgcn_global_load_lds(AS1(As1 + ko), AS3(dsta + bo + 4096),  16, 0, 0);
    __builtin_amdgcn_global_load_lds(AS1(Bs0 + ko), AS3(dsta + bo + 8192),  16, 0, 0);
    __builtin_amdgcn_global_load_lds(AS1(Bs1 + ko), AS3(dsta + bo + 12288), 16, 0, 0);
  };

  stage(0); stage(1); stage(2);

  const unsigned short* Ard = lds + (wr * 128 + fr) * 32 + csel;
  const unsigned short* Brd = lds + 8192 + (wc * 64 + fr) * 32 + csel;

#pragma unroll 1
  for (int kt = 0; kt < nkt; ++kt) {
    if (kt + 3 < nkt) {
      stage(kt + 3);
      asm volatile("s_waitcnt vmcnt(12)" ::: "memory");   // tile kt landed
    } else if (kt + 2 < nkt) {
      asm volatile("s_waitcnt vmcnt(8)" ::: "memory");
    } else if (kt + 1 < nkt) {
      asm volatile("s_waitcnt vmcnt(4)" ::: "memory");
    } else {
      asm volatile("s_waitcnt vmcnt(0)" ::: "memory");
    }
    __builtin_amdgcn_s_barrier();
    const int bo = (kt & 3) * 16384;
    bf16x8 b4[4], a8[8];
#pragma unroll
    for (int nj = 0; nj < 4; ++nj) b4[nj] = *(const bf16x8*)(Brd + bo + nj * 512);
#pragma unroll
    for (int mi = 0; mi < 8; ++mi) a8[mi] = *(const bf16x8*)(Ard + bo + mi * 512);
    __builtin_amdgcn_s_setprio(1);
#pragma unroll
    for (int mi = 0; mi < 8; ++mi)
#pragma unroll
      for (int nj = 0; nj < 4; ++nj)
        acc[mi][nj] = __builtin_amdgcn_mfma_f32_16x16x32_bf16(a8[mi], b4[nj], acc[mi][nj], 0, 0, 0);
    __builtin_amdgcn_s_setprio(0);
    __builtin_amdgcn_s_barrier();   // WAR guard: all reads consumed above
  }
}

// ---- Q/K/V projections on core256; Q/K get RoPE; V computed AS Vt ---------
// Grid (384): XCD-chunked bijective remap (384 = 8*48), then
//   swz 0..127 -> Q tile, 128..255 -> K, 256..383 -> V.
// Q/K tile t: m0 = (t>>2)*256 tokens, n0 = (t&3)*256 features.
// V tile t:   d0 = (t&3)*256,  s0 = (t>>2)*256 (global token col).
__global__ __launch_bounds__(512, 2) void proj_rope(
    const unsigned short* __restrict__ xb,
    const unsigned short* __restrict__ Wq, const unsigned short* __restrict__ Wk,
    const unsigned short* __restrict__ Wv,
    const float* __restrict__ bq, const float* __restrict__ bk, const float* __restrict__ bv,
    unsigned short* __restrict__ Q, unsigned short* __restrict__ Ko,
    unsigned short* __restrict__ Vt) {
  __shared__ unsigned short lds[65536];   // 128 KiB: GEMM 4-buf, then repack
  const int bid = blockIdx.x;
  const int swz = (bid & 7) * 48 + (bid >> 3);    // bijective XCD chunking
  const int which = swz >> 7;                     // 0 Q, 1 K, 2 V
  const int t = swz & 127;
  const int tid = threadIdx.x, lane = tid & 63, w = tid >> 6;
  const int wr = w >> 2, wc = w & 3;
  const int cl = lane & 15, q4 = lane >> 4;

  f32x4 acc[8][4];
#pragma unroll
  for (int i = 0; i < 8; i++)
#pragma unroll
    for (int j = 0; j < 4; j++)
#pragma unroll
      for (int k = 0; k < 4; k++) acc[i][j][k] = 0.0f;

  if (which == 2) {
    // ---- V path: Vt[d,s] = sum_k Wv[d,k] x[s,k]; A = Wv (m=d), B = x (n=s)
    const int m0 = (t & 3) * 256;                 // d tile
    const int n0 = (t >> 2) * 256;                // global s tile
    core256(Wv + (long long)m0 * 1024, 1024, xb + (long long)n0 * 1024, 1024, 32, acc, lds);
    const int b = n0 >> 11, sloc = n0 & 2047;
    unsigned short* Outb = Vt + (long long)b * 1024 * 2048;
#pragma unroll
    for (int r = 0; r < 2; ++r) {
      __syncthreads();
      if (wr == r) {
#pragma unroll
        for (int mi = 0; mi < 8; ++mi) {
          const int lr = mi * 16 + q4 * 4;        // 0..127 within round
#pragma unroll
          for (int rr = 0; rr < 4; ++rr) {
            const float b_ = bv[m0 + r * 128 + lr + rr];   // bias per d-row
#pragma unroll
            for (int nj = 0; nj < 4; ++nj)
              lds[(lr + rr) * 264 + wc * 64 + nj * 16 + cl] = f2bf(acc[mi][nj][rr] + b_);
          }
        }
      }
      __syncthreads();
#pragma unroll
      for (int it = 0; it < 8; ++it) {
        int c = it * 512 + tid;
        int row = c >> 5, c8 = (c & 31) << 3;     // 128 rows x 256 cols
        bf16x8 v = *(const bf16x8*)(lds + row * 264 + c8);
        *(bf16x8*)(Outb + (long long)(m0 + r * 128 + row) * 2048 + sloc + c8) = v;
      }
    }
    return;
  }

  // ---- Q/K path: bias + RoPE (native sin/cos) ----
  const int m0 = (t >> 2) * 256;      // token rows
  const int n0 = (t & 3) * 256;       // feature cols
  const unsigned short* W = which == 0 ? Wq : Wk;
  const float* bias = which == 0 ? bq : bk;
  unsigned short* Out = which == 0 ? Q : Ko;

  core256(xb + (long long)m0 * 1024, 1024, W + (long long)n0 * 1024, 1024, 32, acc, lds);

  const float NEG_L2T_512 = -0.025952563239354392f;  // -log2(10000)/512
  const float INV2PI = 0.15915494309189535f;
  float freqn[4];
#pragma unroll
  for (int nj = 0; nj < 4; ++nj) {
    int gn = n0 + wc * 64 + nj * 16 + cl;
    freqn[nj] = exp2f(NEG_L2T_512 * (float)(gn >> 1));
  }
#pragma unroll
  for (int r = 0; r < 2; ++r) {
    __syncthreads();
    if (wr == r) {
#pragma unroll
      for (int mi = 0; mi < 8; ++mi) {
        const int lr = mi * 16 + q4 * 4;
        const int t0 = ((m0 + r * 128) & 2047) + lr;  // batch-local time
#pragma unroll
        for (int nj = 0; nj < 4; ++nj) {
          const int gn = n0 + wc * 64 + nj * 16 + cl;
          const float bi = bias[gn];
#pragma unroll
          for (int rr = 0; rr < 4; ++rr) {
            float v = acc[mi][nj][rr] + bi;
            float partner = __shfl_xor(v, 1, 64);
            float ang = (float)(t0 + rr) * freqn[nj];
            float rev = ang * INV2PI;
            rev = rev - floorf(rev);           // v_sin/v_cos domain
            float c_ = __builtin_amdgcn_cosf(rev);
            float s_ = __builtin_amdgcn_sinf(rev);
            v = v * c_ + ((gn & 1) ? partner : -partner) * s_;
            lds[(lr + rr) * 264 + wc * 64 + nj * 16 + cl] = f2bf(v);
          }
        }
      }
    }
    __syncthreads();
#pragma unroll
    for (int it = 0; it < 8; ++it) {
      int c = it * 512 + tid;
      int row = c >> 5, c8 = (c & 31) << 3;
      bf16x8 v = *(const bf16x8*)(lds + row * 264 + c8);
      *(bf16x8*)(Out + (long long)(m0 + r * 128 + row) * 1024 + n0 + c8) = v;
    }
  }
}

// ---- P = exp(Q K^T / sqrt(C)) (causal-zeroed), bf16; row sums via atomics -
__global__ __launch_bounds__(256) void score_exp(const unsigned short* __restrict__ Q,
                                                 const unsigned short* __restrict__ Kk,
                                                 unsigned short* __restrict__ P,
                                                 float* __restrict__ row_sum) {
  __shared__ unsigned short sh[8192];
  const int bx = blockIdx.x;
  int i = (int)((sqrtf(8.0f * (float)bx + 1.0f) - 1.0f) * 0.5f);
  while ((i + 1) * (i + 2) / 2 <= bx) ++i;
  while (i * (i + 1) / 2 > bx) --i;
  const int j = bx - i * (i + 1) / 2;       // 0..i
  const int b = blockIdx.z;
  const int m0 = i * 128, n0 = j * 128;
  const unsigned short* Qb = Q + (long long)b * 2048 * 1024;
  const unsigned short* Kb = Kk + (long long)b * 2048 * 1024;
  unsigned short* Pb = P + (long long)b * 2048 * 2048;
  float* rs = row_sum + b * 2048;

  f32x4 acc[4][4];
#pragma unroll
  for (int ii = 0; ii < 4; ii++)
#pragma unroll
    for (int jj = 0; jj < 4; jj++)
#pragma unroll
      for (int k = 0; k < 4; k++) acc[ii][jj][k] = 0.0f;

  gemm_core(Qb + (long long)m0 * 1024, 1024, Kb + (long long)n0 * 1024, 1024, 1024, acc, sh, sh + 4096);

  const int tid = threadIdx.x, lane = tid & 63, w = tid >> 6;
  const int wm = (w & 1) << 6, wn = (w >> 1) << 6;
  const int cl = lane & 15, q4 = lane >> 4;
  const bool diag = (i == j);
#pragma unroll
  for (int mi = 0; mi < 4; mi++) {
    unsigned short vals[4][4];
    float rsum[4] = {0.f, 0.f, 0.f, 0.f};
#pragma unroll
    for (int ni = 0; ni < 4; ni++) {
      const int gn = n0 + wn + ni * 16 + cl;
#pragma unroll
      for (int rr = 0; rr < 4; rr++) {
        const int gm = m0 + wm + mi * 16 + q4 * 4 + rr;
        float e = (diag && gn > gm) ? 0.0f : __expf(acc[mi][ni][rr] * 0.03125f);
        vals[ni][rr] = f2bf(e);
        rsum[rr] += e;
      }
    }
#pragma unroll
    for (int rr = 0; rr < 4; rr++) {
#pragma unroll
      for (int off = 1; off < 16; off <<= 1) rsum[rr] += __shfl_xor(rsum[rr], off, 64);
    }
    if (cl == 0) {
      const int gm = m0 + wm + mi * 16 + q4 * 4;
#pragma unroll
      for (int rr = 0; rr < 4; rr++) atomicAdd(&rs[gm + rr], rsum[rr]);
    }
    repack_store_mi(vals, sh, mi, m0, n0, 2048, Pb);
  }
}

// ---- O = (P V) / row_sum; longest-K blocks dispatched first ---------------
__global__ __launch_bounds__(256) void pv_gemm(const unsigned short* __restrict__ P,
                                               const unsigned short* __restrict__ Vt,
                                               const float* __restrict__ row_sum,
                                               unsigned short* __restrict__ O) {
  __shared__ unsigned short sh[8192];
  const int b = blockIdx.z;
  const int mt = 15 - blockIdx.x;   // longest K first (tail balance)
  const int m0 = mt * 128;          // t tile
  const int n0 = blockIdx.y * 128;  // d tile
  const unsigned short* Pb = P + (long long)b * 2048 * 2048;
  const unsigned short* Vb = Vt + (long long)b * 1024 * 2048;
  const float* rs = row_sum + b * 2048;
  const int K = m0 + 128;  // causal: P[t, s>t] == 0 beyond this

  f32x4 acc[4][4];
#pragma unroll
  for (int i = 0; i < 4; i++)
#pragma unroll
    for (int j = 0; j < 4; j++)
#pragma unroll
      for (int k = 0; k < 4; k++) acc[i][j][k] = 0.0f;

  gemm_core(Pb + (long long)m0 * 2048, 2048, Vb + (long long)n0 * 2048, 2048, K, acc, sh, sh + 4096);

  const int tid = threadIdx.x, lane = tid & 63, w = tid >> 6;
  const int wm = (w & 1) << 6;
  const int q4 = lane >> 4;
#pragma unroll
  for (int mi = 0; mi < 4; mi++) {
    unsigned short vals[4][4];
    float inv[4];
    const int gm0 = m0 + wm + mi * 16 + q4 * 4;
#pragma unroll
    for (int rr = 0; rr < 4; rr++) inv[rr] = 1.0f / rs[gm0 + rr];
#pragma unroll
    for (int ni = 0; ni < 4; ni++)
#pragma unroll
      for (int rr = 0; rr < 4; rr++)
        vals[ni][rr] = f2bf(acc[mi][ni][rr] * inv[rr]);
    repack_store_mi(vals, sh, mi, m0, n0, 1024, O + (long long)b * 2048 * 1024);
  }
}

// ---- out = O Wf^T + bf, fp32 out (core4, 512 thr) -------------------------
__global__ __launch_bounds__(512, 2) void final_gemm(const unsigned short* __restrict__ O,
                                                     const unsigned short* __restrict__ Wf,
                                                     const float* __restrict__ bf_,
                                                     float* __restrict__ out) {
  __shared__ unsigned short lds[49152];
  float* shf = (float*)lds;
  const int tid = threadIdx.x, lane = tid & 63, w = tid >> 6;
  const int wr = w >> 2, wc = w & 3;
  const int cl = lane & 15, q4 = lane >> 4;
  const int m0 = blockIdx.x * 128;
  const int n0 = blockIdx.y * 256;

  f32x4 acc[4][4];
#pragma unroll
  for (int i = 0; i < 4; i++)
#pragma unroll
    for (int j = 0; j < 4; j++)
#pragma unroll
      for (int k = 0; k < 4; k++) acc[i][j][k] = 0.0f;

  core4(O + (long long)m0 * 1024, 1024, Wf + (long long)n0 * 1024, 1024, 32, acc, lds);

  // fp32 repack in two 64-row rounds (64 x 260 floats = 66.5 KB <= 96 KB)
#pragma unroll
  for (int r = 0; r < 2; ++r) {
    __syncthreads();
    if (wr == r) {
#pragma unroll
      for (int mi = 0; mi < 4; ++mi)
#pragma unroll
        for (int nj = 0; nj < 4; ++nj) {
          const int col = wc * 64 + nj * 16 + cl;
          const float bi = bf_[n0 + col];
#pragma unroll
          for (int rr = 0; rr < 4; ++rr)
            shf[(mi * 16 + q4 * 4 + rr) * 260 + col] = acc[mi][nj][rr] + bi;
        }
    }
    __syncthreads();
#pragma unroll
    for (int it = 0; it < 8; ++it) {
      int c = it * 512 + tid;
      int row = c >> 6, c4 = (c & 63) << 2;
      float4 v = *(const float4*)(shf + row * 260 + c4);
      *(float4*)(out + (long long)(m0 + r * 64 + row) * 1024 + n0 + c4) = v;
    }
  }
}

// ---------------------------------------------------------------------------
extern "C" void kernel_launch(void* const* d_in, const int* in_sizes, int n_in,
                              void* d_out, int out_size, void* d_ws, size_t ws_size,
                              hipStream_t stream) {
  (void)in_sizes; (void)n_in; (void)out_size; (void)ws_size;
  const float* x   = (const float*)d_in[0];
  const float* Wq  = (const float*)d_in[1];
  const float* bq  = (const float*)d_in[2];
  const float* Wk  = (const float*)d_in[3];
  const float* bk  = (const float*)d_in[4];
  const float* Wv  = (const float*)d_in[5];
  const float* bv  = (const float*)d_in[6];
  const float* Wf  = (const float*)d_in[7];
  const float* bf_ = (const float*)d_in[8];
  float* out = (float*)d_out;

  char* ws = (char*)d_ws;
  const size_t MB = 1024 * 1024;
  unsigned short* xb  = (unsigned short*)(ws);             // 16 MB
  unsigned short* Wqb = (unsigned short*)(ws + 16 * MB);   // 2 MB
  unsigned short* Wkb = (unsigned short*)(ws + 18 * MB);   // 2 MB
  unsigned short* Wvb = (unsigned short*)(ws + 20 * MB);   // 2 MB
  unsigned short* Wfb = (unsigned short*)(ws + 22 * MB);   // 2 MB
  unsigned short* Qb  = (unsigned short*)(ws + 24 * MB);   // 16 MB
  unsigned short* Kb  = (unsigned short*)(ws + 40 * MB);   // 16 MB
  unsigned short* Vtb = (unsigned short*)(ws + 56 * MB);   // 16 MB
  unsigned short* Ob  = (unsigned short*)(ws + 72 * MB);   // 16 MB
  unsigned short* Pb  = (unsigned short*)(ws + 88 * MB);   // 32 MB P bf16
  float*          rsum= (float*)(ws + 120 * MB);           // 32 KB row sums

  hipMemsetAsync(rsum, 0, 8192 * sizeof(float), stream);
  cast_all<<<dim3(3145728 / 256), dim3(256), 0, stream>>>(x, Wq, Wk, Wv, Wf, xb, Wqb, Wkb, Wvb, Wfb);
  proj_rope<<<dim3(384), dim3(512), 0, stream>>>(xb, Wqb, Wkb, Wvb, bq, bk, bv, Qb, Kb, Vtb);
  score_exp<<<dim3(136, 1, 4), dim3(256), 0, stream>>>(Qb, Kb, Pb, rsum);
  pv_gemm<<<dim3(16, 8, 4), dim3(256), 0, stream>>>(Pb, Vtb, rsum, Ob);
  final_gemm<<<dim3(64, 4), dim3(512), 0, stream>>>(Ob, Wfb, bf_, out);
}

// Round 5
// 311.514 us; speedup vs baseline: 1.0163x; 1.0163x over previous
//
#include <hip/hip_runtime.h>
#include <math.h>

// ---------------------------------------------------------------------------
// MultiChannelAttention on MI355X (gfx950)
// out = softmax(causal(rope(xWq^T) rope(xWk^T)^T / sqrt(C))) (xWv^T) Wf^T + b
// B=4 T=2048 C=1024. bf16 MFMA (16x16x32), fp32 accum.
// R13: core256 + R11's proven reg-dbuf pipeline (R12 removed it -> 136us
//      latency stall). Partial dbuf sized for VGPR budget: {A-low, B} of
//      tile kt+1 read under tile kt's MFMA (64 VGPR dbuf); A-high of tile
//      kt read in-body as the OLDEST ds_reads, consumed after 16 free
//      MFMAs (latency hidden). vmcnt(8) certify (4 loads/tile, 3 tiles in
//      flight), 2 barriers/K-tile. ~105 VGPR + 128 AGPR: fits 2 waves/SIMD.
// R12 (regressed): in-body fragment reads -> serial ds latency per K-tile.
// R11: core4 software pipeline (reg-dbuf fragments, counted vmcnt).
// R8: V projection computes Vt natively (A=Wv, B=x). R7: triangular score
//     grid; pv longest-K-first. R5: native v_sin/v_cos RoPE. R2: fused
//     exp-softmax (P=exp(s) bf16 + atomic row sums).
// Workspace layout (121 MB):
//   [0,16) xb  [16,24) Wq/Wk/Wv/Wf bf16  [24,40) Q  [40,56) K
//   [56,72) Vt  [72,88) O  [88,120) P bf16  [120,+32K) row_sum
// ---------------------------------------------------------------------------

#define AS1(p) ((__attribute__((address_space(1))) void*)(p))
#define AS3(p) ((__attribute__((address_space(3))) void*)(p))

typedef __attribute__((ext_vector_type(8))) short bf16x8;
typedef __attribute__((ext_vector_type(4))) float f32x4;

__device__ __forceinline__ unsigned short f2bf(float f) {
  unsigned int u = __float_as_uint(f);
  u += 0x7fffu + ((u >> 16) & 1u);   // round-to-nearest-even
  return (unsigned short)(u >> 16);
}

// ---- fp32 -> bf16 cast for x + 4 weight matrices, one launch --------------
__global__ __launch_bounds__(256) void cast_all(
    const float* __restrict__ x, const float* __restrict__ Wq,
    const float* __restrict__ Wk, const float* __restrict__ Wv,
    const float* __restrict__ Wf,
    unsigned short* __restrict__ xb, unsigned short* __restrict__ Wqb,
    unsigned short* __restrict__ Wkb, unsigned short* __restrict__ Wvb,
    unsigned short* __restrict__ Wfb) {
  int i = blockIdx.x * 256 + threadIdx.x;           // float4 index
  const float* src; unsigned short* dst; int off;
  if (i < 2097152) { src = x; dst = xb; off = i; }
  else {
    int j = i - 2097152;
    int w = j >> 18; off = j & 262143;              // 262144 float4 per W
    src = (w == 0) ? Wq : (w == 1) ? Wk : (w == 2) ? Wv : Wf;
    dst = (w == 0) ? Wqb : (w == 1) ? Wkb : (w == 2) ? Wvb : Wfb;
  }
  float4 f = ((const float4*)src)[off];
  ushort4 o;
  o.x = f2bf(f.x); o.y = f2bf(f.y); o.z = f2bf(f.z); o.w = f2bf(f.w);
  ((ushort4*)dst)[off] = o;
}

// ---- legacy 128x128 bt-GEMM core (256 thr), used by score_exp / pv_gemm ---
__device__ __forceinline__ void gemm_core(const unsigned short* __restrict__ At, long long lda,
                                          const unsigned short* __restrict__ Bt, long long ldb,
                                          int K, f32x4 (&acc)[4][4],
                                          unsigned short* As, unsigned short* Bs) {
  const int tid  = threadIdx.x;
  const int lane = tid & 63;
  const int w    = tid >> 6;
  const int wm   = (w & 1) << 6;
  const int wn   = (w >> 1) << 6;
  const int fr   = lane & 15;
  const int fq   = lane >> 4;
  const int srow = tid >> 2;
  const int scol = (tid & 3) << 3;
  const int lg   = ((tid & 3) ^ ((srow >> 1) & 3)) << 3;
  const unsigned short* a0 = At + (long long)srow * lda + lg;
  const unsigned short* a1 = At + (long long)(srow + 64) * lda + lg;
  const unsigned short* b0 = Bt + (long long)srow * ldb + lg;
  const unsigned short* b1 = Bt + (long long)(srow + 64) * ldb + lg;
  unsigned short* As0 = As + srow * 32 + scol;
  unsigned short* As1 = As + (srow + 64) * 32 + scol;
  unsigned short* Bs0 = Bs + srow * 32 + scol;
  unsigned short* Bs1 = Bs + (srow + 64) * 32 + scol;
  const int pg = (fq ^ ((fr >> 1) & 3)) << 3;
  for (int k0 = 0; k0 < K; k0 += 32) {
    __builtin_amdgcn_global_load_lds(AS1(a0 + k0), AS3(As0), 16, 0, 0);
    __builtin_amdgcn_global_load_lds(AS1(a1 + k0), AS3(As1), 16, 0, 0);
    __builtin_amdgcn_global_load_lds(AS1(b0 + k0), AS3(Bs0), 16, 0, 0);
    __builtin_amdgcn_global_load_lds(AS1(b1 + k0), AS3(Bs1), 16, 0, 0);
    __syncthreads();
    bf16x8 af[4], bfr[4];
#pragma unroll
    for (int i = 0; i < 4; i++)
      af[i] = *(const bf16x8*)(As + (wm + i * 16 + fr) * 32 + pg);
#pragma unroll
    for (int i = 0; i < 4; i++)
      bfr[i] = *(const bf16x8*)(Bs + (wn + i * 16 + fr) * 32 + pg);
#pragma unroll
    for (int mi = 0; mi < 4; mi++)
#pragma unroll
      for (int ni = 0; ni < 4; ni++)
        acc[mi][ni] = __builtin_amdgcn_mfma_f32_16x16x32_bf16(af[mi], bfr[ni], acc[mi][ni], 0, 0, 0);
    __syncthreads();
  }
}

// ---- LDS repack + coalesced bf16x8 store of one mi-slice (legacy) ---------
__device__ __forceinline__ void repack_store_mi(unsigned short (&vals)[4][4],
                                                unsigned short* sh, int mi,
                                                int m0, int n0, long long ldo,
                                                unsigned short* __restrict__ Out) {
  const int tid = threadIdx.x, lane = tid & 63, w = tid >> 6;
  const int half = w & 1, wn = (w >> 1) << 6;
  const int cl = lane & 15, q4 = lane >> 4;
  const int lr = half * 16 + q4 * 4;
#pragma unroll
  for (int ni = 0; ni < 4; ni++)
#pragma unroll
    for (int rr = 0; rr < 4; rr++)
      sh[(lr + rr) * 132 + wn + ni * 16 + cl] = vals[ni][rr];
  __syncthreads();
#pragma unroll
  for (int it = 0; it < 2; ++it) {
    int row = (tid >> 4) + it * 16;          // 0..31
    int c8 = (tid & 15) << 3;                // 0..120
    bf16x8 v = *(const bf16x8*)(sh + row * 132 + c8);
    int gr = m0 + (row < 16 ? mi * 16 + row : 48 + mi * 16 + row);
    *(bf16x8*)(Out + (long long)gr * ldo + n0 + c8) = v;
  }
  __syncthreads();
}

// ---------------------------------------------------------------------------
// core4 (kept for final_gemm): 128x256 tile, per-wave 64x64, BK=32, 4 LDS
// buffers, 3-deep prefetch, reg-dbuf fragments. See R11 notes.
// ---------------------------------------------------------------------------
__device__ __forceinline__ void core4(
    const unsigned short* __restrict__ A, long long lda,
    const unsigned short* __restrict__ B, long long ldb,
    int nkt, f32x4 (&acc)[4][4], unsigned short* lds) {
  const int tid  = threadIdx.x;
  const int lane = tid & 63;
  const int w    = tid >> 6;
  const int wr   = w >> 2;            // 0..1
  const int wc   = w & 3;             // 0..3
  const int fr   = lane & 15;
  const int fq   = lane >> 4;
  const int csel = (fq ^ ((fr >> 1) & 3)) << 3;   // fragment chunk swizzle
  const int srow = tid >> 2;                      // staging row 0..127
  const int scsw = ((tid & 3) ^ ((srow >> 1) & 3)) << 3;
  const unsigned short* Asrc  = A + (long long)srow * lda + scsw;
  const unsigned short* Bsrc0 = B + (long long)srow * ldb + scsw;
  const unsigned short* Bsrc1 = B + (long long)(srow + 128) * ldb + scsw;
  unsigned short* dsta = lds + tid * 8;           // per-thread 16B slot

  auto stage = [&](int kt) {
    const int bo = (kt & 3) * 12288;
    const long long ko = (long long)kt * 32;
    __builtin_amdgcn_global_load_lds(AS1(Asrc + ko),  AS3(dsta + bo),        16, 0, 0);
    __builtin_amdgcn_global_load_lds(AS1(Bsrc0 + ko), AS3(dsta + bo + 4096), 16, 0, 0);
    __builtin_amdgcn_global_load_lds(AS1(Bsrc1 + ko), AS3(dsta + bo + 8192), 16, 0, 0);
  };
  auto rdfrag = [&](int kt, bf16x8 (&r)[8]) {
    const unsigned short* Ab = lds + (kt & 3) * 12288 + (wr * 64 + fr) * 32 + csel;
    const unsigned short* Bb = lds + (kt & 3) * 12288 + 4096 + (wc * 64 + fr) * 32 + csel;
#pragma unroll
    for (int mi = 0; mi < 4; ++mi) r[mi] = *(const bf16x8*)(Ab + mi * 512);
#pragma unroll
    for (int nj = 0; nj < 4; ++nj) r[4 + nj] = *(const bf16x8*)(Bb + nj * 512);
  };

  bf16x8 ra[8], rb[8];
  stage(0); stage(1); stage(2);
  asm volatile("s_waitcnt vmcnt(6)" ::: "memory");
  __builtin_amdgcn_s_barrier();
  rdfrag(0, ra);

  auto body = [&](int kt, bf16x8 (&cur)[8], bf16x8 (&nxt)[8]) {
    if (kt + 3 < nkt) {
      stage(kt + 3);
      asm volatile("s_waitcnt vmcnt(6)" ::: "memory");
    } else if (kt + 2 < nkt) {
      asm volatile("s_waitcnt vmcnt(3)" ::: "memory");
    } else if (kt + 1 < nkt) {
      asm volatile("s_waitcnt vmcnt(0)" ::: "memory");
    }
    if (kt + 1 < nkt) {
      __builtin_amdgcn_s_barrier();
      rdfrag(kt + 1, nxt);
    }
    __builtin_amdgcn_s_setprio(1);
#pragma unroll
    for (int mi = 0; mi < 4; ++mi)
#pragma unroll
      for (int nj = 0; nj < 4; ++nj)
        acc[mi][nj] = __builtin_amdgcn_mfma_f32_16x16x32_bf16(cur[mi], cur[4 + nj], acc[mi][nj], 0, 0, 0);
    __builtin_amdgcn_s_setprio(0);
    if (kt + 1 < nkt) __builtin_amdgcn_s_barrier();
  };

#pragma unroll 1
  for (int kt = 0; kt < nkt; kt += 2) {
    body(kt, ra, rb);
    body(kt + 1, rb, ra);
  }
}

// ---------------------------------------------------------------------------
// core256 (R13): 256x256 block tile, 512 thr = 8 waves (2M x 4N), per-wave
// 128x64 (acc[8][4]). BK=32; 4 LDS buffers of 32 KiB = 128 KiB:
//   buf kt&3 at (kt&3)*16384 shorts: A[256][32] at +0, B[256][32] at +8192.
// 16B chunks swizzled c ^= (row>>1)&3 (pre-swizzled GLOBAL source, linear
// LDS dest; sel = fq ^ ((fr>>1)&3) on reads -- balanced banks).
// Pipeline (R11 pattern, partial reg-dbuf):
//   - 3 K-tiles of global prefetch in flight (12 loads), vmcnt(8) certifies
//     tile kt+1 at iter kt.
//   - dbuf'd fragments: {A-low(4), B(4)} of tile kt+1 read after the certify
//     barrier, drain under tile kt's 32 MFMA, consumed at iter kt+1.
//   - in-body: A-high(4) of tile kt read FIRST (oldest lgkm), consumed after
//     16 no-wait MFMAs -> latency hidden.
// 2 barriers + 32 MFMA per wave per K-tile. C[m,n] = sum_k A[m,k]*B[n,k].
// nkt even, >= 4.
// ---------------------------------------------------------------------------
__device__ __forceinline__ void core256(
    const unsigned short* __restrict__ A, long long lda,
    const unsigned short* __restrict__ B, long long ldb,
    int nkt, f32x4 (&acc)[8][4], unsigned short* lds) {
  const int tid  = threadIdx.x;
  const int lane = tid & 63;
  const int w    = tid >> 6;
  const int wr   = w >> 2;            // 0..1  (M half: rows wr*128..+128)
  const int wc   = w & 3;             // 0..3  (N quarter: cols wc*64..+64)
  const int fr   = lane & 15;
  const int fq   = lane >> 4;
  const int csel = (fq ^ ((fr >> 1) & 3)) << 3;
  const int srow = tid >> 2;          // 0..127
  const int scsw = ((tid & 3) ^ ((srow >> 1) & 3)) << 3;
  const unsigned short* As0 = A + (long long)srow * lda + scsw;
  const unsigned short* As1 = A + (long long)(srow + 128) * lda + scsw;
  const unsigned short* Bs0 = B + (long long)srow * ldb + scsw;
  const unsigned short* Bs1 = B + (long long)(srow + 128) * ldb + scsw;
  unsigned short* dsta = lds + tid * 8;

  auto stage = [&](int kt) {
    const int bo = (kt & 3) * 16384;
    const long long ko = (long long)kt * 32;
    __builtin_amdgcn_global_load_lds(AS1(As0 + ko), AS3(dsta + bo),         16, 0, 0);
    __builtin_amdgcn_global_load_lds(AS1(As1 + ko), AS3(dsta + bo + 4096),  16, 0, 0);
    __builtin_amdgcn_global_load_lds(AS1(Bs0 + ko), AS3(dsta + bo + 8192),  16, 0, 0);
    __builtin_amdgcn_global_load_lds(AS1(Bs1 + ko), AS3(dsta + bo + 12288), 16, 0, 0);
  };

  const unsigned short* Ard = lds + (wr * 128 + fr) * 32 + csel;
  const unsigned short* Brd = lds + 8192 + (wc * 64 + fr) * 32 + csel;

  auto rdAB = [&](int kt, bf16x8 (&aL)[4], bf16x8 (&b4)[4]) {
    const int bo = (kt & 3) * 16384;
#pragma unroll
    for (int nj = 0; nj < 4; ++nj) b4[nj] = *(const bf16x8*)(Brd + bo + nj * 512);
#pragma unroll
    for (int mi = 0; mi < 4; ++mi) aL[mi] = *(const bf16x8*)(Ard + bo + mi * 512);
  };

  bf16x8 aLa[4], b4a[4], aLb[4], b4b[4];
  // prologue: 3 tiles in flight; certify tile 0; preload its {A-low, B}
  stage(0); stage(1); stage(2);
  asm volatile("s_waitcnt vmcnt(8)" ::: "memory");
  __builtin_amdgcn_s_barrier();
  rdAB(0, aLa, b4a);

  auto body = [&](int kt, bf16x8 (&aLc)[4], bf16x8 (&b4c)[4],
                  bf16x8 (&aLn)[4], bf16x8 (&b4n)[4]) {
    if (kt + 3 < nkt) {
      stage(kt + 3);
      asm volatile("s_waitcnt vmcnt(8)" ::: "memory");   // tile kt+1 landed
    } else if (kt + 2 < nkt) {
      asm volatile("s_waitcnt vmcnt(4)" ::: "memory");
    } else if (kt + 1 < nkt) {
      asm volatile("s_waitcnt vmcnt(0)" ::: "memory");
    }
    __builtin_amdgcn_s_barrier();      // tile kt+1 visible to all waves
    // in-body A-high of tile kt: OLDEST ds_reads this iter (earliest retire)
    bf16x8 aH[4];
    const int bo = (kt & 3) * 16384;
#pragma unroll
    for (int mi = 0; mi < 4; ++mi) aH[mi] = *(const bf16x8*)(Ard + bo + (4 + mi) * 512);
    if (kt + 1 < nkt) rdAB(kt + 1, aLn, b4n);   // drains under MFMA below
    __builtin_amdgcn_s_setprio(1);
#pragma unroll
    for (int mi = 0; mi < 4; ++mi)              // no-wait: regs from last iter
#pragma unroll
      for (int nj = 0; nj < 4; ++nj)
        acc[mi][nj] = __builtin_amdgcn_mfma_f32_16x16x32_bf16(aLc[mi], b4c[nj], acc[mi][nj], 0, 0, 0);
#pragma unroll
    for (int mi = 0; mi < 4; ++mi)              // aH arrives under the above
#pragma unroll
      for (int nj = 0; nj < 4; ++nj)
        acc[4 + mi][nj] = __builtin_amdgcn_mfma_f32_16x16x32_bf16(aH[mi], b4c[nj], acc[4 + mi][nj], 0, 0, 0);
    __builtin_amdgcn_s_setprio(0);
    if (kt + 1 < nkt) __builtin_amdgcn_s_barrier();  // WAR guard
  };

#pragma unroll 1
  for (int kt = 0; kt < nkt; kt += 2) {   // reg ping-pong, nkt even
    body(kt, aLa, b4a, aLb, b4b);
    body(kt + 1, aLb, b4b, aLa, b4a);
  }
}

// ---- Q/K/V projections on core256; Q/K get RoPE; V computed AS Vt ---------
// Grid (384): XCD-chunked bijective remap (384 = 8*48), then
//   swz 0..127 -> Q tile, 128..255 -> K, 256..383 -> V.
// Q/K tile t: m0 = (t>>2)*256 tokens, n0 = (t&3)*256 features.
// V tile t:   d0 = (t&3)*256,  s0 = (t>>2)*256 (global token col).
__global__ __launch_bounds__(512, 2) void proj_rope(
    const unsigned short* __restrict__ xb,
    const unsigned short* __restrict__ Wq, const unsigned short* __restrict__ Wk,
    const unsigned short* __restrict__ Wv,
    const float* __restrict__ bq, const float* __restrict__ bk, const float* __restrict__ bv,
    unsigned short* __restrict__ Q, unsigned short* __restrict__ Ko,
    unsigned short* __restrict__ Vt) {
  __shared__ unsigned short lds[65536];   // 128 KiB: GEMM 4-buf, then repack
  const int bid = blockIdx.x;
  const int swz = (bid & 7) * 48 + (bid >> 3);    // bijective XCD chunking
  const int which = swz >> 7;                     // 0 Q, 1 K, 2 V
  const int t = swz & 127;
  const int tid = threadIdx.x, lane = tid & 63, w = tid >> 6;
  const int wr = w >> 2, wc = w & 3;
  const int cl = lane & 15, q4 = lane >> 4;

  f32x4 acc[8][4];
#pragma unroll
  for (int i = 0; i < 8; i++)
#pragma unroll
    for (int j = 0; j < 4; j++)
#pragma unroll
      for (int k = 0; k < 4; k++) acc[i][j][k] = 0.0f;

  if (which == 2) {
    // ---- V path: Vt[d,s] = sum_k Wv[d,k] x[s,k]; A = Wv (m=d), B = x (n=s)
    const int m0 = (t & 3) * 256;                 // d tile
    const int n0 = (t >> 2) * 256;                // global s tile
    core256(Wv + (long long)m0 * 1024, 1024, xb + (long long)n0 * 1024, 1024, 32, acc, lds);
    const int b = n0 >> 11, sloc = n0 & 2047;
    unsigned short* Outb = Vt + (long long)b * 1024 * 2048;
#pragma unroll
    for (int r = 0; r < 2; ++r) {
      __syncthreads();
      if (wr == r) {
#pragma unroll
        for (int mi = 0; mi < 8; ++mi) {
          const int lr = mi * 16 + q4 * 4;        // 0..127 within round
#pragma unroll
          for (int rr = 0; rr < 4; ++rr) {
            const float b_ = bv[m0 + r * 128 + lr + rr];   // bias per d-row
#pragma unroll
            for (int nj = 0; nj < 4; ++nj)
              lds[(lr + rr) * 264 + wc * 64 + nj * 16 + cl] = f2bf(acc[mi][nj][rr] + b_);
          }
        }
      }
      __syncthreads();
#pragma unroll
      for (int it = 0; it < 8; ++it) {
        int c = it * 512 + tid;
        int row = c >> 5, c8 = (c & 31) << 3;     // 128 rows x 256 cols
        bf16x8 v = *(const bf16x8*)(lds + row * 264 + c8);
        *(bf16x8*)(Outb + (long long)(m0 + r * 128 + row) * 2048 + sloc + c8) = v;
      }
    }
    return;
  }

  // ---- Q/K path: bias + RoPE (native sin/cos) ----
  const int m0 = (t >> 2) * 256;      // token rows
  const int n0 = (t & 3) * 256;       // feature cols
  const unsigned short* W = which == 0 ? Wq : Wk;
  const float* bias = which == 0 ? bq : bk;
  unsigned short* Out = which == 0 ? Q : Ko;

  core256(xb + (long long)m0 * 1024, 1024, W + (long long)n0 * 1024, 1024, 32, acc, lds);

  const float NEG_L2T_512 = -0.025952563239354392f;  // -log2(10000)/512
  const float INV2PI = 0.15915494309189535f;
  float freqn[4];
#pragma unroll
  for (int nj = 0; nj < 4; ++nj) {
    int gn = n0 + wc * 64 + nj * 16 + cl;
    freqn[nj] = exp2f(NEG_L2T_512 * (float)(gn >> 1));
  }
#pragma unroll
  for (int r = 0; r < 2; ++r) {
    __syncthreads();
    if (wr == r) {
#pragma unroll
      for (int mi = 0; mi < 8; ++mi) {
        const int lr = mi * 16 + q4 * 4;
        const int t0 = ((m0 + r * 128) & 2047) + lr;  // batch-local time
#pragma unroll
        for (int nj = 0; nj < 4; ++nj) {
          const int gn = n0 + wc * 64 + nj * 16 + cl;
          const float bi = bias[gn];
#pragma unroll
          for (int rr = 0; rr < 4; ++rr) {
            float v = acc[mi][nj][rr] + bi;
            float partner = __shfl_xor(v, 1, 64);
            float ang = (float)(t0 + rr) * freqn[nj];
            float rev = ang * INV2PI;
            rev = rev - floorf(rev);           // v_sin/v_cos domain
            float c_ = __builtin_amdgcn_cosf(rev);
            float s_ = __builtin_amdgcn_sinf(rev);
            v = v * c_ + ((gn & 1) ? partner : -partner) * s_;
            lds[(lr + rr) * 264 + wc * 64 + nj * 16 + cl] = f2bf(v);
          }
        }
      }
    }
    __syncthreads();
#pragma unroll
    for (int it = 0; it < 8; ++it) {
      int c = it * 512 + tid;
      int row = c >> 5, c8 = (c & 31) << 3;
      bf16x8 v = *(const bf16x8*)(lds + row * 264 + c8);
      *(bf16x8*)(Out + (long long)(m0 + r * 128 + row) * 1024 + n0 + c8) = v;
    }
  }
}

// ---- P = exp(Q K^T / sqrt(C)) (causal-zeroed), bf16; row sums via atomics -
__global__ __launch_bounds__(256) void score_exp(const unsigned short* __restrict__ Q,
                                                 const unsigned short* __restrict__ Kk,
                                                 unsigned short* __restrict__ P,
                                                 float* __restrict__ row_sum) {
  __shared__ unsigned short sh[8192];
  const int bx = blockIdx.x;
  int i = (int)((sqrtf(8.0f * (float)bx + 1.0f) - 1.0f) * 0.5f);
  while ((i + 1) * (i + 2) / 2 <= bx) ++i;
  while (i * (i + 1) / 2 > bx) --i;
  const int j = bx - i * (i + 1) / 2;       // 0..i
  const int b = blockIdx.z;
  const int m0 = i * 128, n0 = j * 128;
  const unsigned short* Qb = Q + (long long)b * 2048 * 1024;
  const unsigned short* Kb = Kk + (long long)b * 2048 * 1024;
  unsigned short* Pb = P + (long long)b * 2048 * 2048;
  float* rs = row_sum + b * 2048;

  f32x4 acc[4][4];
#pragma unroll
  for (int ii = 0; ii < 4; ii++)
#pragma unroll
    for (int jj = 0; jj < 4; jj++)
#pragma unroll
      for (int k = 0; k < 4; k++) acc[ii][jj][k] = 0.0f;

  gemm_core(Qb + (long long)m0 * 1024, 1024, Kb + (long long)n0 * 1024, 1024, 1024, acc, sh, sh + 4096);

  const int tid = threadIdx.x, lane = tid & 63, w = tid >> 6;
  const int wm = (w & 1) << 6, wn = (w >> 1) << 6;
  const int cl = lane & 15, q4 = lane >> 4;
  const bool diag = (i == j);
#pragma unroll
  for (int mi = 0; mi < 4; mi++) {
    unsigned short vals[4][4];
    float rsum[4] = {0.f, 0.f, 0.f, 0.f};
#pragma unroll
    for (int ni = 0; ni < 4; ni++) {
      const int gn = n0 + wn + ni * 16 + cl;
#pragma unroll
      for (int rr = 0; rr < 4; rr++) {
        const int gm = m0 + wm + mi * 16 + q4 * 4 + rr;
        float e = (diag && gn > gm) ? 0.0f : __expf(acc[mi][ni][rr] * 0.03125f);
        vals[ni][rr] = f2bf(e);
        rsum[rr] += e;
      }
    }
#pragma unroll
    for (int rr = 0; rr < 4; rr++) {
#pragma unroll
      for (int off = 1; off < 16; off <<= 1) rsum[rr] += __shfl_xor(rsum[rr], off, 64);
    }
    if (cl == 0) {
      const int gm = m0 + wm + mi * 16 + q4 * 4;
#pragma unroll
      for (int rr = 0; rr < 4; rr++) atomicAdd(&rs[gm + rr], rsum[rr]);
    }
    repack_store_mi(vals, sh, mi, m0, n0, 2048, Pb);
  }
}

// ---- O = (P V) / row_sum; longest-K blocks dispatched first ---------------
__global__ __launch_bounds__(256) void pv_gemm(const unsigned short* __restrict__ P,
                                               const unsigned short* __restrict__ Vt,
                                               const float* __restrict__ row_sum,
                                               unsigned short* __restrict__ O) {
  __shared__ unsigned short sh[8192];
  const int b = blockIdx.z;
  const int mt = 15 - blockIdx.x;   // longest K first (tail balance)
  const int m0 = mt * 128;          // t tile
  const int n0 = blockIdx.y * 128;  // d tile
  const unsigned short* Pb = P + (long long)b * 2048 * 2048;
  const unsigned short* Vb = Vt + (long long)b * 1024 * 2048;
  const float* rs = row_sum + b * 2048;
  const int K = m0 + 128;  // causal: P[t, s>t] == 0 beyond this

  f32x4 acc[4][4];
#pragma unroll
  for (int i = 0; i < 4; i++)
#pragma unroll
    for (int j = 0; j < 4; j++)
#pragma unroll
      for (int k = 0; k < 4; k++) acc[i][j][k] = 0.0f;

  gemm_core(Pb + (long long)m0 * 2048, 2048, Vb + (long long)n0 * 2048, 2048, K, acc, sh, sh + 4096);

  const int tid = threadIdx.x, lane = tid & 63, w = tid >> 6;
  const int wm = (w & 1) << 6;
  const int q4 = lane >> 4;
#pragma unroll
  for (int mi = 0; mi < 4; mi++) {
    unsigned short vals[4][4];
    float inv[4];
    const int gm0 = m0 + wm + mi * 16 + q4 * 4;
#pragma unroll
    for (int rr = 0; rr < 4; rr++) inv[rr] = 1.0f / rs[gm0 + rr];
#pragma unroll
    for (int ni = 0; ni < 4; ni++)
#pragma unroll
      for (int rr = 0; rr < 4; rr++)
        vals[ni][rr] = f2bf(acc[mi][ni][rr] * inv[rr]);
    repack_store_mi(vals, sh, mi, m0, n0, 1024, O + (long long)b * 2048 * 1024);
  }
}

// ---- out = O Wf^T + bf, fp32 out (core4, 512 thr) -------------------------
__global__ __launch_bounds__(512, 2) void final_gemm(const unsigned short* __restrict__ O,
                                                     const unsigned short* __restrict__ Wf,
                                                     const float* __restrict__ bf_,
                                                     float* __restrict__ out) {
  __shared__ unsigned short lds[49152];
  float* shf = (float*)lds;
  const int tid = threadIdx.x, lane = tid & 63, w = tid >> 6;
  const int wr = w >> 2, wc = w & 3;
  const int cl = lane & 15, q4 = lane >> 4;
  const int m0 = blockIdx.x * 128;
  const int n0 = blockIdx.y * 256;

  f32x4 acc[4][4];
#pragma unroll
  for (int i = 0; i < 4; i++)
#pragma unroll
    for (int j = 0; j < 4; j++)
#pragma unroll
      for (int k = 0; k < 4; k++) acc[i][j][k] = 0.0f;

  core4(O + (long long)m0 * 1024, 1024, Wf + (long long)n0 * 1024, 1024, 32, acc, lds);

  // fp32 repack in two 64-row rounds (64 x 260 floats = 66.5 KB <= 96 KB)
#pragma unroll
  for (int r = 0; r < 2; ++r) {
    __syncthreads();
    if (wr == r) {
#pragma unroll
      for (int mi = 0; mi < 4; ++mi)
#pragma unroll
        for (int nj = 0; nj < 4; ++nj) {
          const int col = wc * 64 + nj * 16 + cl;
          const float bi = bf_[n0 + col];
#pragma unroll
          for (int rr = 0; rr < 4; ++rr)
            shf[(mi * 16 + q4 * 4 + rr) * 260 + col] = acc[mi][nj][rr] + bi;
        }
    }
    __syncthreads();
#pragma unroll
    for (int it = 0; it < 8; ++it) {
      int c = it * 512 + tid;
      int row = c >> 6, c4 = (c & 63) << 2;
      float4 v = *(const float4*)(shf + row * 260 + c4);
      *(float4*)(out + (long long)(m0 + r * 64 + row) * 1024 + n0 + c4) = v;
    }
  }
}

// ---------------------------------------------------------------------------
extern "C" void kernel_launch(void* const* d_in, const int* in_sizes, int n_in,
                              void* d_out, int out_size, void* d_ws, size_t ws_size,
                              hipStream_t stream) {
  (void)in_sizes; (void)n_in; (void)out_size; (void)ws_size;
  const float* x   = (const float*)d_in[0];
  const float* Wq  = (const float*)d_in[1];
  const float* bq  = (const float*)d_in[2];
  const float* Wk  = (const float*)d_in[3];
  const float* bk  = (const float*)d_in[4];
  const float* Wv  = (const float*)d_in[5];
  const float* bv  = (const float*)d_in[6];
  const float* Wf  = (const float*)d_in[7];
  const float* bf_ = (const float*)d_in[8];
  float* out = (float*)d_out;

  char* ws = (char*)d_ws;
  const size_t MB = 1024 * 1024;
  unsigned short* xb  = (unsigned short*)(ws);             // 16 MB
  unsigned short* Wqb = (unsigned short*)(ws + 16 * MB);   // 2 MB
  unsigned short* Wkb = (unsigned short*)(ws + 18 * MB);   // 2 MB
  unsigned short* Wvb = (unsigned short*)(ws + 20 * MB);   // 2 MB
  unsigned short* Wfb = (unsigned short*)(ws + 22 * MB);   // 2 MB
  unsigned short* Qb  = (unsigned short*)(ws + 24 * MB);   // 16 MB
  unsigned short* Kb  = (unsigned short*)(ws + 40 * MB);   // 16 MB
  unsigned short* Vtb = (unsigned short*)(ws + 56 * MB);   // 16 MB
  unsigned short* Ob  = (unsigned short*)(ws + 72 * MB);   // 16 MB
  unsigned short* Pb  = (unsigned short*)(ws + 88 * MB);   // 32 MB P bf16
  float*          rsum= (float*)(ws + 120 * MB);           // 32 KB row sums

  hipMemsetAsync(rsum, 0, 8192 * sizeof(float), stream);
  cast_all<<<dim3(3145728 / 256), dim3(256), 0, stream>>>(x, Wq, Wk, Wv, Wf, xb, Wqb, Wkb, Wvb, Wfb);
  proj_rope<<<dim3(384), dim3(512), 0, stream>>>(xb, Wqb, Wkb, Wvb, bq, bk, bv, Qb, Kb, Vtb);
  score_exp<<<dim3(136, 1, 4), dim3(256), 0, stream>>>(Qb, Kb, Pb, rsum);
  pv_gemm<<<dim3(16, 8, 4), dim3(256), 0, stream>>>(Pb, Vtb, rsum, Ob);
  final_gemm<<<dim3(64, 4), dim3(512), 0, stream>>>(Ob, Wfb, bf_, out);
}

// Round 6
// 290.241 us; speedup vs baseline: 1.0908x; 1.0733x over previous
//
#include <hip/hip_runtime.h>
#include <math.h>

// ---------------------------------------------------------------------------
// MultiChannelAttention on MI355X (gfx950)
// out = softmax(causal(rope(xWq^T) rope(xWk^T)^T / sqrt(C))) (xWv^T) Wf^T + b
// B=4 T=2048 C=1024. bf16 MFMA (16x16x32), fp32 accum.
// R14: score_exp + pv_gemm moved off the legacy vmcnt(0)-drain core onto
//      core4h -- the R11-verified pipeline at 256 thr / 128x128 tile
//      (4 LDS bufs x 16 KiB = 64 KiB -> 2 blocks/CU, 3-deep prefetch,
//      counted vmcnt(8), reg-dbuf fragments). Reconciled totals showed
//      score+pv = ~170 us (58% of runtime) at ~220 TF -- the real hotspot.
//      proj_rope/final_gemm reverted to R11's exact best-measured code.
// R13/R12 (256^2 core experiments): regressed, reverted.
// R11: core4 software pipeline (reg-dbuf fragments, counted vmcnt).
// R8: V projection computes Vt natively (A=Wv, B=x). R7: triangular score
//     grid; pv longest-K-first. R5: native v_sin/v_cos RoPE. R2: fused
//     exp-softmax (P=exp(s) bf16 + atomic row sums).
// Workspace layout (121 MB):
//   [0,16) xb  [16,24) Wq/Wk/Wv/Wf bf16  [24,40) Q  [40,56) K
//   [56,72) Vt  [72,88) O  [88,120) P bf16  [120,+32K) row_sum
// ---------------------------------------------------------------------------

#define AS1(p) ((__attribute__((address_space(1))) void*)(p))
#define AS3(p) ((__attribute__((address_space(3))) void*)(p))

typedef __attribute__((ext_vector_type(8))) short bf16x8;
typedef __attribute__((ext_vector_type(4))) float f32x4;

__device__ __forceinline__ unsigned short f2bf(float f) {
  unsigned int u = __float_as_uint(f);
  u += 0x7fffu + ((u >> 16) & 1u);   // round-to-nearest-even
  return (unsigned short)(u >> 16);
}

// ---- fp32 -> bf16 cast for x + 4 weight matrices, one launch --------------
__global__ __launch_bounds__(256) void cast_all(
    const float* __restrict__ x, const float* __restrict__ Wq,
    const float* __restrict__ Wk, const float* __restrict__ Wv,
    const float* __restrict__ Wf,
    unsigned short* __restrict__ xb, unsigned short* __restrict__ Wqb,
    unsigned short* __restrict__ Wkb, unsigned short* __restrict__ Wvb,
    unsigned short* __restrict__ Wfb) {
  int i = blockIdx.x * 256 + threadIdx.x;           // float4 index
  const float* src; unsigned short* dst; int off;
  if (i < 2097152) { src = x; dst = xb; off = i; }
  else {
    int j = i - 2097152;
    int w = j >> 18; off = j & 262143;              // 262144 float4 per W
    src = (w == 0) ? Wq : (w == 1) ? Wk : (w == 2) ? Wv : Wf;
    dst = (w == 0) ? Wqb : (w == 1) ? Wkb : (w == 2) ? Wvb : Wfb;
  }
  float4 f = ((const float4*)src)[off];
  ushort4 o;
  o.x = f2bf(f.x); o.y = f2bf(f.y); o.z = f2bf(f.z); o.w = f2bf(f.w);
  ((ushort4*)dst)[off] = o;
}

// ---- LDS repack + coalesced bf16x8 store of one mi-slice (256 thr) --------
__device__ __forceinline__ void repack_store_mi(unsigned short (&vals)[4][4],
                                                unsigned short* sh, int mi,
                                                int m0, int n0, long long ldo,
                                                unsigned short* __restrict__ Out) {
  const int tid = threadIdx.x, lane = tid & 63, w = tid >> 6;
  const int half = w & 1, wn = (w >> 1) << 6;
  const int cl = lane & 15, q4 = lane >> 4;
  const int lr = half * 16 + q4 * 4;
#pragma unroll
  for (int ni = 0; ni < 4; ni++)
#pragma unroll
    for (int rr = 0; rr < 4; rr++)
      sh[(lr + rr) * 132 + wn + ni * 16 + cl] = vals[ni][rr];
  __syncthreads();
#pragma unroll
  for (int it = 0; it < 2; ++it) {
    int row = (tid >> 4) + it * 16;          // 0..31
    int c8 = (tid & 15) << 3;                // 0..120
    bf16x8 v = *(const bf16x8*)(sh + row * 132 + c8);
    int gr = m0 + (row < 16 ? mi * 16 + row : 48 + mi * 16 + row);
    *(bf16x8*)(Out + (long long)gr * ldo + n0 + c8) = v;
  }
  __syncthreads();
}

// ---------------------------------------------------------------------------
// core4 (proj/final): 128x256 tile, 512 thr = 8 waves (2M x 4N), per-wave
// 64x64 (acc[4][4]). BK=32; 4 LDS buffers of 24 KiB; 3-deep global prefetch
// (vmcnt(6) certify); reg-dbuf fragments: tile kt+1's ds_reads issue after
// the certify barrier and drain under tile kt's 16 MFMA. 2 barriers/K-tile.
// 16B chunks swizzled c ^= (row>>1)&3, pre-swizzled global source, linear
// LDS dest. C[m,n] = sum_k A[m,k]*B[n,k], A/B bf16 K-fast. nkt even >= 4.
// ---------------------------------------------------------------------------
__device__ __forceinline__ void core4(
    const unsigned short* __restrict__ A, long long lda,
    const unsigned short* __restrict__ B, long long ldb,
    int nkt, f32x4 (&acc)[4][4], unsigned short* lds) {
  const int tid  = threadIdx.x;
  const int lane = tid & 63;
  const int w    = tid >> 6;
  const int wr   = w >> 2;            // 0..1
  const int wc   = w & 3;             // 0..3
  const int fr   = lane & 15;
  const int fq   = lane >> 4;
  const int csel = (fq ^ ((fr >> 1) & 3)) << 3;   // fragment chunk swizzle
  const int srow = tid >> 2;                      // staging row 0..127
  const int scsw = ((tid & 3) ^ ((srow >> 1) & 3)) << 3;
  const unsigned short* Asrc  = A + (long long)srow * lda + scsw;
  const unsigned short* Bsrc0 = B + (long long)srow * ldb + scsw;
  const unsigned short* Bsrc1 = B + (long long)(srow + 128) * ldb + scsw;
  unsigned short* dsta = lds + tid * 8;           // per-thread 16B slot

  auto stage = [&](int kt) {
    const int bo = (kt & 3) * 12288;
    const long long ko = (long long)kt * 32;
    __builtin_amdgcn_global_load_lds(AS1(Asrc + ko),  AS3(dsta + bo),        16, 0, 0);
    __builtin_amdgcn_global_load_lds(AS1(Bsrc0 + ko), AS3(dsta + bo + 4096), 16, 0, 0);
    __builtin_amdgcn_global_load_lds(AS1(Bsrc1 + ko), AS3(dsta + bo + 8192), 16, 0, 0);
  };
  auto rdfrag = [&](int kt, bf16x8 (&r)[8]) {
    const unsigned short* Ab = lds + (kt & 3) * 12288 + (wr * 64 + fr) * 32 + csel;
    const unsigned short* Bb = lds + (kt & 3) * 12288 + 4096 + (wc * 64 + fr) * 32 + csel;
#pragma unroll
    for (int mi = 0; mi < 4; ++mi) r[mi] = *(const bf16x8*)(Ab + mi * 512);
#pragma unroll
    for (int nj = 0; nj < 4; ++nj) r[4 + nj] = *(const bf16x8*)(Bb + nj * 512);
  };

  bf16x8 ra[8], rb[8];
  stage(0); stage(1); stage(2);
  asm volatile("s_waitcnt vmcnt(6)" ::: "memory");
  __builtin_amdgcn_s_barrier();
  rdfrag(0, ra);

  auto body = [&](int kt, bf16x8 (&cur)[8], bf16x8 (&nxt)[8]) {
    if (kt + 3 < nkt) {
      stage(kt + 3);
      asm volatile("s_waitcnt vmcnt(6)" ::: "memory");
    } else if (kt + 2 < nkt) {
      asm volatile("s_waitcnt vmcnt(3)" ::: "memory");
    } else if (kt + 1 < nkt) {
      asm volatile("s_waitcnt vmcnt(0)" ::: "memory");
    }
    if (kt + 1 < nkt) {
      __builtin_amdgcn_s_barrier();
      rdfrag(kt + 1, nxt);
    }
    __builtin_amdgcn_s_setprio(1);
#pragma unroll
    for (int mi = 0; mi < 4; ++mi)
#pragma unroll
      for (int nj = 0; nj < 4; ++nj)
        acc[mi][nj] = __builtin_amdgcn_mfma_f32_16x16x32_bf16(cur[mi], cur[4 + nj], acc[mi][nj], 0, 0, 0);
    __builtin_amdgcn_s_setprio(0);
    if (kt + 1 < nkt) __builtin_amdgcn_s_barrier();
  };

#pragma unroll 1
  for (int kt = 0; kt < nkt; kt += 2) {
    body(kt, ra, rb);
    body(kt + 1, rb, ra);
  }
}

// ---------------------------------------------------------------------------
// core4h (score/pv): core4 re-parameterized to 256 thr / 128x128 tile.
// 4 waves (2M x 2N), per-wave 64x64 (acc[4][4]). BK=32; 4 LDS buffers of
// 16 KiB = 64 KiB (-> 2 blocks/CU); stage = 4 global_load_lds (A 2, B 2);
// 3-deep prefetch, certify gates vmcnt(8)/(4)/(0); reg-dbuf fragments;
// 2 barriers/K-tile. Same chunk swizzle (row keys are ==(fr>>1)&3 since all
// row offsets are multiples of 16). nkt even >= 4.
// ---------------------------------------------------------------------------
__device__ __forceinline__ void core4h(
    const unsigned short* __restrict__ A, long long lda,
    const unsigned short* __restrict__ B, long long ldb,
    int nkt, f32x4 (&acc)[4][4], unsigned short* lds) {
  const int tid  = threadIdx.x;          // 0..255
  const int lane = tid & 63;
  const int w    = tid >> 6;             // 0..3
  const int wm   = (w & 1) << 6;         // M half
  const int wn   = (w >> 1) << 6;        // N half
  const int fr   = lane & 15;
  const int fq   = lane >> 4;
  const int csel = (fq ^ ((fr >> 1) & 3)) << 3;
  const int srow = tid >> 2;             // 0..63
  const int scsw = ((tid & 3) ^ ((srow >> 1) & 3)) << 3;
  const unsigned short* Asrc0 = A + (long long)srow * lda + scsw;
  const unsigned short* Asrc1 = A + (long long)(srow + 64) * lda + scsw;
  const unsigned short* Bsrc0 = B + (long long)srow * ldb + scsw;
  const unsigned short* Bsrc1 = B + (long long)(srow + 64) * ldb + scsw;
  unsigned short* dsta = lds + tid * 8;  // 16B per thread per instr

  auto stage = [&](int kt) {
    const int bo = (kt & 3) * 8192;
    const long long ko = (long long)kt * 32;
    __builtin_amdgcn_global_load_lds(AS1(Asrc0 + ko), AS3(dsta + bo),        16, 0, 0);
    __builtin_amdgcn_global_load_lds(AS1(Asrc1 + ko), AS3(dsta + bo + 2048), 16, 0, 0);
    __builtin_amdgcn_global_load_lds(AS1(Bsrc0 + ko), AS3(dsta + bo + 4096), 16, 0, 0);
    __builtin_amdgcn_global_load_lds(AS1(Bsrc1 + ko), AS3(dsta + bo + 6144), 16, 0, 0);
  };
  auto rdfrag = [&](int kt, bf16x8 (&r)[8]) {
    const unsigned short* Ab = lds + (kt & 3) * 8192 + (wm + fr) * 32 + csel;
    const unsigned short* Bb = lds + (kt & 3) * 8192 + 4096 + (wn + fr) * 32 + csel;
#pragma unroll
    for (int mi = 0; mi < 4; ++mi) r[mi] = *(const bf16x8*)(Ab + mi * 512);
#pragma unroll
    for (int nj = 0; nj < 4; ++nj) r[4 + nj] = *(const bf16x8*)(Bb + nj * 512);
  };

  bf16x8 ra[8], rb[8];
  stage(0); stage(1); stage(2);
  asm volatile("s_waitcnt vmcnt(8)" ::: "memory");
  __builtin_amdgcn_s_barrier();
  rdfrag(0, ra);

  auto body = [&](int kt, bf16x8 (&cur)[8], bf16x8 (&nxt)[8]) {
    if (kt + 3 < nkt) {
      stage(kt + 3);
      asm volatile("s_waitcnt vmcnt(8)" ::: "memory");
    } else if (kt + 2 < nkt) {
      asm volatile("s_waitcnt vmcnt(4)" ::: "memory");
    } else if (kt + 1 < nkt) {
      asm volatile("s_waitcnt vmcnt(0)" ::: "memory");
    }
    if (kt + 1 < nkt) {
      __builtin_amdgcn_s_barrier();
      rdfrag(kt + 1, nxt);
    }
    __builtin_amdgcn_s_setprio(1);
#pragma unroll
    for (int mi = 0; mi < 4; ++mi)
#pragma unroll
      for (int nj = 0; nj < 4; ++nj)
        acc[mi][nj] = __builtin_amdgcn_mfma_f32_16x16x32_bf16(cur[mi], cur[4 + nj], acc[mi][nj], 0, 0, 0);
    __builtin_amdgcn_s_setprio(0);
    if (kt + 1 < nkt) __builtin_amdgcn_s_barrier();
  };

#pragma unroll 1
  for (int kt = 0; kt < nkt; kt += 2) {
    body(kt, ra, rb);
    body(kt + 1, rb, ra);
  }
}

// ---- Q/K/V projections; Q/K get RoPE; V computed AS Vt (swapped operands) -
// Grid (64, 4, 3), 512 threads. Q/K: x=m-tile(128), y=n-tile(256).
// V: bijective XCD remap for L2 locality.
__global__ __launch_bounds__(512, 2) void proj_rope(
    const unsigned short* __restrict__ xb,
    const unsigned short* __restrict__ Wq, const unsigned short* __restrict__ Wk,
    const unsigned short* __restrict__ Wv,
    const float* __restrict__ bq, const float* __restrict__ bk, const float* __restrict__ bv,
    unsigned short* __restrict__ Q, unsigned short* __restrict__ Ko,
    unsigned short* __restrict__ Vt) {
  __shared__ unsigned short lds[49152];   // 96 KiB: GEMM 4-buf, then repack
  const int which = blockIdx.z;
  const int tid = threadIdx.x, lane = tid & 63, w = tid >> 6;
  const int wr = w >> 2, wc = w & 3;
  const int cl = lane & 15, q4 = lane >> 4;

  f32x4 acc[4][4];
#pragma unroll
  for (int i = 0; i < 4; i++)
#pragma unroll
    for (int j = 0; j < 4; j++)
#pragma unroll
      for (int k = 0; k < 4; k++) acc[i][j][k] = 0.0f;

  if (which == 2) {
    // ---- V path: Vt[d,s] = sum_k Wv[d,k] x[s,k]; A = Wv (m=d), B = x (n=s)
    const int p = blockIdx.x + 64 * blockIdx.y;     // physical 0..255
    const int m0 = ((p >> 3) & 7) * 128;            // d tile
    const int n0 = (4 * (p & 7) + (p >> 6)) * 256;  // global s tile (XCD remap)
    core4(Wv + (long long)m0 * 1024, 1024, xb + (long long)n0 * 1024, 1024, 32, acc, lds);
    __syncthreads();
    const int b = n0 >> 11, sloc = n0 & 2047;
#pragma unroll
    for (int mi = 0; mi < 4; ++mi) {
      const int lr = wr * 64 + mi * 16 + q4 * 4;
#pragma unroll
      for (int rr = 0; rr < 4; ++rr) {
        const float b_ = bv[m0 + lr + rr];          // bias per d-row
#pragma unroll
        for (int nj = 0; nj < 4; ++nj)
          lds[(lr + rr) * 264 + wc * 64 + nj * 16 + cl] = f2bf(acc[mi][nj][rr] + b_);
      }
    }
    __syncthreads();
    unsigned short* Outb = Vt + (long long)b * 1024 * 2048;
#pragma unroll
    for (int it = 0; it < 8; ++it) {
      int c = it * 512 + tid;
      int row = c >> 5, c8 = (c & 31) << 3;
      bf16x8 v = *(const bf16x8*)(lds + row * 264 + c8);
      *(bf16x8*)(Outb + (long long)(m0 + row) * 2048 + sloc + c8) = v;
    }
    return;
  }

  // ---- Q/K path: bias + RoPE (native sin/cos) ----
  const int m0 = blockIdx.x * 128;    // token rows
  const int n0 = blockIdx.y * 256;    // feature cols
  const unsigned short* W = which == 0 ? Wq : Wk;
  const float* bias = which == 0 ? bq : bk;
  unsigned short* Out = which == 0 ? Q : Ko;

  core4(xb + (long long)m0 * 1024, 1024, W + (long long)n0 * 1024, 1024, 32, acc, lds);
  __syncthreads();

  const float NEG_L2T_512 = -0.025952563239354392f;  // -log2(10000)/512
  const float INV2PI = 0.15915494309189535f;
  float freqn[4];
#pragma unroll
  for (int nj = 0; nj < 4; ++nj) {
    int gn = n0 + wc * 64 + nj * 16 + cl;
    freqn[nj] = exp2f(NEG_L2T_512 * (float)(gn >> 1));
  }
#pragma unroll
  for (int mi = 0; mi < 4; ++mi) {
    const int lr = wr * 64 + mi * 16 + q4 * 4;
    const int t0 = (m0 & 2047) + lr;   // batch-local time (tiles never straddle)
#pragma unroll
    for (int nj = 0; nj < 4; ++nj) {
      const int gn = n0 + wc * 64 + nj * 16 + cl;
      const float bi = bias[gn];
#pragma unroll
      for (int rr = 0; rr < 4; ++rr) {
        float v = acc[mi][nj][rr] + bi;
        float partner = __shfl_xor(v, 1, 64);
        float ang = (float)(t0 + rr) * freqn[nj];
        float rev = ang * INV2PI;
        rev = rev - floorf(rev);           // v_sin/v_cos domain
        float c_ = __builtin_amdgcn_cosf(rev);
        float s_ = __builtin_amdgcn_sinf(rev);
        v = v * c_ + ((gn & 1) ? partner : -partner) * s_;
        lds[(lr + rr) * 264 + wc * 64 + nj * 16 + cl] = f2bf(v);
      }
    }
  }
  __syncthreads();
#pragma unroll
  for (int it = 0; it < 8; ++it) {
    int c = it * 512 + tid;
    int row = c >> 5, c8 = (c & 31) << 3;
    bf16x8 v = *(const bf16x8*)(lds + row * 264 + c8);
    *(bf16x8*)(Out + (long long)(m0 + row) * 1024 + n0 + c8) = v;
  }
}

// ---- P = exp(Q K^T / sqrt(C)) (causal-zeroed), bf16; row sums via atomics -
// core4h pipelined GEMM; epilogue unchanged.
__global__ __launch_bounds__(256, 2) void score_exp(const unsigned short* __restrict__ Q,
                                                    const unsigned short* __restrict__ Kk,
                                                    unsigned short* __restrict__ P,
                                                    float* __restrict__ row_sum) {
  __shared__ unsigned short sh[32768];   // 64 KiB: 4 GEMM bufs, then repack
  const int bx = blockIdx.x;
  int i = (int)((sqrtf(8.0f * (float)bx + 1.0f) - 1.0f) * 0.5f);
  while ((i + 1) * (i + 2) / 2 <= bx) ++i;
  while (i * (i + 1) / 2 > bx) --i;
  const int j = bx - i * (i + 1) / 2;       // 0..i
  const int b = blockIdx.z;
  const int m0 = i * 128, n0 = j * 128;
  const unsigned short* Qb = Q + (long long)b * 2048 * 1024;
  const unsigned short* Kb = Kk + (long long)b * 2048 * 1024;
  unsigned short* Pb = P + (long long)b * 2048 * 2048;
  float* rs = row_sum + b * 2048;

  f32x4 acc[4][4];
#pragma unroll
  for (int ii = 0; ii < 4; ii++)
#pragma unroll
    for (int jj = 0; jj < 4; jj++)
#pragma unroll
      for (int k = 0; k < 4; k++) acc[ii][jj][k] = 0.0f;

  core4h(Qb + (long long)m0 * 1024, 1024, Kb + (long long)n0 * 1024, 1024, 32, acc, sh);
  __syncthreads();

  const int tid = threadIdx.x, lane = tid & 63, w = tid >> 6;
  const int wm = (w & 1) << 6, wn = (w >> 1) << 6;
  const int cl = lane & 15, q4 = lane >> 4;
  const bool diag = (i == j);
#pragma unroll
  for (int mi = 0; mi < 4; mi++) {
    unsigned short vals[4][4];
    float rsum[4] = {0.f, 0.f, 0.f, 0.f};
#pragma unroll
    for (int ni = 0; ni < 4; ni++) {
      const int gn = n0 + wn + ni * 16 + cl;
#pragma unroll
      for (int rr = 0; rr < 4; rr++) {
        const int gm = m0 + wm + mi * 16 + q4 * 4 + rr;
        float e = (diag && gn > gm) ? 0.0f : __expf(acc[mi][ni][rr] * 0.03125f);
        vals[ni][rr] = f2bf(e);
        rsum[rr] += e;
      }
    }
#pragma unroll
    for (int rr = 0; rr < 4; rr++) {
#pragma unroll
      for (int off = 1; off < 16; off <<= 1) rsum[rr] += __shfl_xor(rsum[rr], off, 64);
    }
    if (cl == 0) {
      const int gm = m0 + wm + mi * 16 + q4 * 4;
#pragma unroll
      for (int rr = 0; rr < 4; rr++) atomicAdd(&rs[gm + rr], rsum[rr]);
    }
    repack_store_mi(vals, sh, mi, m0, n0, 2048, Pb);
  }
}

// ---- O = (P V) / row_sum; longest-K blocks dispatched first ---------------
// core4h pipelined GEMM; epilogue unchanged.
__global__ __launch_bounds__(256, 2) void pv_gemm(const unsigned short* __restrict__ P,
                                                  const unsigned short* __restrict__ Vt,
                                                  const float* __restrict__ row_sum,
                                                  unsigned short* __restrict__ O) {
  __shared__ unsigned short sh[32768];   // 64 KiB: 4 GEMM bufs, then repack
  const int b = blockIdx.z;
  const int mt = 15 - blockIdx.x;   // longest K first (tail balance)
  const int m0 = mt * 128;          // t tile
  const int n0 = blockIdx.y * 128;  // d tile
  const unsigned short* Pb = P + (long long)b * 2048 * 2048;
  const unsigned short* Vb = Vt + (long long)b * 1024 * 2048;
  const float* rs = row_sum + b * 2048;
  const int nkt = 4 * (mt + 1);     // K = m0+128 -> K/32, even >= 4

  f32x4 acc[4][4];
#pragma unroll
  for (int i = 0; i < 4; i++)
#pragma unroll
    for (int j = 0; j < 4; j++)
#pragma unroll
      for (int k = 0; k < 4; k++) acc[i][j][k] = 0.0f;

  core4h(Pb + (long long)m0 * 2048, 2048, Vb + (long long)n0 * 2048, 2048, nkt, acc, sh);
  __syncthreads();

  const int tid = threadIdx.x, lane = tid & 63, w = tid >> 6;
  const int wm = (w & 1) << 6;
  const int q4 = lane >> 4;
#pragma unroll
  for (int mi = 0; mi < 4; mi++) {
    unsigned short vals[4][4];
    float inv[4];
    const int gm0 = m0 + wm + mi * 16 + q4 * 4;
#pragma unroll
    for (int rr = 0; rr < 4; rr++) inv[rr] = 1.0f / rs[gm0 + rr];
#pragma unroll
    for (int ni = 0; ni < 4; ni++)
#pragma unroll
      for (int rr = 0; rr < 4; rr++)
        vals[ni][rr] = f2bf(acc[mi][ni][rr] * inv[rr]);
    repack_store_mi(vals, sh, mi, m0, n0, 1024, O + (long long)b * 2048 * 1024);
  }
}

// ---- out = O Wf^T + bf, fp32 out (core4, 512 thr) -------------------------
__global__ __launch_bounds__(512, 2) void final_gemm(const unsigned short* __restrict__ O,
                                                     const unsigned short* __restrict__ Wf,
                                                     const float* __restrict__ bf_,
                                                     float* __restrict__ out) {
  __shared__ unsigned short lds[49152];
  float* shf = (float*)lds;
  const int tid = threadIdx.x, lane = tid & 63, w = tid >> 6;
  const int wr = w >> 2, wc = w & 3;
  const int cl = lane & 15, q4 = lane >> 4;
  const int m0 = blockIdx.x * 128;
  const int n0 = blockIdx.y * 256;

  f32x4 acc[4][4];
#pragma unroll
  for (int i = 0; i < 4; i++)
#pragma unroll
    for (int j = 0; j < 4; j++)
#pragma unroll
      for (int k = 0; k < 4; k++) acc[i][j][k] = 0.0f;

  core4(O + (long long)m0 * 1024, 1024, Wf + (long long)n0 * 1024, 1024, 32, acc, lds);

  // fp32 repack in two 64-row rounds (64 x 260 floats = 66.5 KB <= 96 KB)
#pragma unroll
  for (int r = 0; r < 2; ++r) {
    __syncthreads();
    if (wr == r) {
#pragma unroll
      for (int mi = 0; mi < 4; ++mi)
#pragma unroll
        for (int nj = 0; nj < 4; ++nj) {
          const int col = wc * 64 + nj * 16 + cl;
          const float bi = bf_[n0 + col];
#pragma unroll
          for (int rr = 0; rr < 4; ++rr)
            shf[(mi * 16 + q4 * 4 + rr) * 260 + col] = acc[mi][nj][rr] + bi;
        }
    }
    __syncthreads();
#pragma unroll
    for (int it = 0; it < 8; ++it) {
      int c = it * 512 + tid;
      int row = c >> 6, c4 = (c & 63) << 2;
      float4 v = *(const float4*)(shf + row * 260 + c4);
      *(float4*)(out + (long long)(m0 + r * 64 + row) * 1024 + n0 + c4) = v;
    }
  }
}

// ---------------------------------------------------------------------------
extern "C" void kernel_launch(void* const* d_in, const int* in_sizes, int n_in,
                              void* d_out, int out_size, void* d_ws, size_t ws_size,
                              hipStream_t stream) {
  (void)in_sizes; (void)n_in; (void)out_size; (void)ws_size;
  const float* x   = (const float*)d_in[0];
  const float* Wq  = (const float*)d_in[1];
  const float* bq  = (const float*)d_in[2];
  const float* Wk  = (const float*)d_in[3];
  const float* bk  = (const float*)d_in[4];
  const float* Wv  = (const float*)d_in[5];
  const float* bv  = (const float*)d_in[6];
  const float* Wf  = (const float*)d_in[7];
  const float* bf_ = (const float*)d_in[8];
  float* out = (float*)d_out;

  char* ws = (char*)d_ws;
  const size_t MB = 1024 * 1024;
  unsigned short* xb  = (unsigned short*)(ws);             // 16 MB
  unsigned short* Wqb = (unsigned short*)(ws + 16 * MB);   // 2 MB
  unsigned short* Wkb = (unsigned short*)(ws + 18 * MB);   // 2 MB
  unsigned short* Wvb = (unsigned short*)(ws + 20 * MB);   // 2 MB
  unsigned short* Wfb = (unsigned short*)(ws + 22 * MB);   // 2 MB
  unsigned short* Qb  = (unsigned short*)(ws + 24 * MB);   // 16 MB
  unsigned short* Kb  = (unsigned short*)(ws + 40 * MB);   // 16 MB
  unsigned short* Vtb = (unsigned short*)(ws + 56 * MB);   // 16 MB
  unsigned short* Ob  = (unsigned short*)(ws + 72 * MB);   // 16 MB
  unsigned short* Pb  = (unsigned short*)(ws + 88 * MB);   // 32 MB P bf16
  float*          rsum= (float*)(ws + 120 * MB);           // 32 KB row sums

  hipMemsetAsync(rsum, 0, 8192 * sizeof(float), stream);
  cast_all<<<dim3(3145728 / 256), dim3(256), 0, stream>>>(x, Wq, Wk, Wv, Wf, xb, Wqb, Wkb, Wvb, Wfb);
  proj_rope<<<dim3(64, 4, 3), dim3(512), 0, stream>>>(xb, Wqb, Wkb, Wvb, bq, bk, bv, Qb, Kb, Vtb);
  score_exp<<<dim3(136, 1, 4), dim3(256), 0, stream>>>(Qb, Kb, Pb, rsum);
  pv_gemm<<<dim3(16, 8, 4), dim3(256), 0, stream>>>(Pb, Vtb, rsum, Ob);
  final_gemm<<<dim3(64, 4), dim3(512), 0, stream>>>(Ob, Wfb, bf_, out);
}

// Round 7
// 289.255 us; speedup vs baseline: 1.0945x; 1.0034x over previous
//
#include <hip/hip_runtime.h>
#include <math.h>

// ---------------------------------------------------------------------------
// MultiChannelAttention on MI355X (gfx950)
// out = softmax(causal(rope(xWq^T) rope(xWk^T)^T / sqrt(C))) (xWv^T) Wf^T + b
// B=4 T=2048 C=1024. bf16 MFMA (16x16x32), fp32 accum.
// R15 (DIAGNOSTIC): proj_rope split into 3 launches (Q/K/V, `which` is now a
//      kernel arg) so each lands ~25us -- below score/pv/final -- forcing the
//      unmeasured kernels into rocprof's top-5. rsum memset fused into
//      cast_all (-1 dispatch) to offset a gap. All compute code is
//      byte-identical to R14. Next round targets whichever kernel the
//      counters convict.
// R14: score/pv on core4h (R11 pipeline @ 256thr/128^2/64KiB): total delta
//      ~0 -> falsified "score+pv are core-bound" theory.
// R11: core4 software pipeline (reg-dbuf fragments, counted vmcnt) -- best
//      measured proj (75.9us) and overall (290.2us with R14's score/pv).
// R8: V projection computes Vt natively (A=Wv, B=x). R7: triangular score
//     grid; pv longest-K-first. R5: native v_sin/v_cos RoPE. R2: fused
//     exp-softmax (P=exp(s) bf16 + atomic row sums).
// Workspace layout (121 MB):
//   [0,16) xb  [16,24) Wq/Wk/Wv/Wf bf16  [24,40) Q  [40,56) K
//   [56,72) Vt  [72,88) O  [88,120) P bf16  [120,+32K) row_sum
// ---------------------------------------------------------------------------

#define AS1(p) ((__attribute__((address_space(1))) void*)(p))
#define AS3(p) ((__attribute__((address_space(3))) void*)(p))

typedef __attribute__((ext_vector_type(8))) short bf16x8;
typedef __attribute__((ext_vector_type(4))) float f32x4;

__device__ __forceinline__ unsigned short f2bf(float f) {
  unsigned int u = __float_as_uint(f);
  u += 0x7fffu + ((u >> 16) & 1u);   // round-to-nearest-even
  return (unsigned short)(u >> 16);
}

// ---- fp32 -> bf16 cast for x + 4 weight matrices, + rsum zero, one launch -
__global__ __launch_bounds__(256) void cast_all(
    const float* __restrict__ x, const float* __restrict__ Wq,
    const float* __restrict__ Wk, const float* __restrict__ Wv,
    const float* __restrict__ Wf,
    unsigned short* __restrict__ xb, unsigned short* __restrict__ Wqb,
    unsigned short* __restrict__ Wkb, unsigned short* __restrict__ Wvb,
    unsigned short* __restrict__ Wfb, float* __restrict__ rsum) {
  int i = blockIdx.x * 256 + threadIdx.x;           // float4 index
  if (i < 8192) rsum[i] = 0.0f;                     // fused memset (32 KB)
  const float* src; unsigned short* dst; int off;
  if (i < 2097152) { src = x; dst = xb; off = i; }
  else {
    int j = i - 2097152;
    int w = j >> 18; off = j & 262143;              // 262144 float4 per W
    src = (w == 0) ? Wq : (w == 1) ? Wk : (w == 2) ? Wv : Wf;
    dst = (w == 0) ? Wqb : (w == 1) ? Wkb : (w == 2) ? Wvb : Wfb;
  }
  float4 f = ((const float4*)src)[off];
  ushort4 o;
  o.x = f2bf(f.x); o.y = f2bf(f.y); o.z = f2bf(f.z); o.w = f2bf(f.w);
  ((ushort4*)dst)[off] = o;
}

// ---- LDS repack + coalesced bf16x8 store of one mi-slice (256 thr) --------
__device__ __forceinline__ void repack_store_mi(unsigned short (&vals)[4][4],
                                                unsigned short* sh, int mi,
                                                int m0, int n0, long long ldo,
                                                unsigned short* __restrict__ Out) {
  const int tid = threadIdx.x, lane = tid & 63, w = tid >> 6;
  const int half = w & 1, wn = (w >> 1) << 6;
  const int cl = lane & 15, q4 = lane >> 4;
  const int lr = half * 16 + q4 * 4;
#pragma unroll
  for (int ni = 0; ni < 4; ni++)
#pragma unroll
    for (int rr = 0; rr < 4; rr++)
      sh[(lr + rr) * 132 + wn + ni * 16 + cl] = vals[ni][rr];
  __syncthreads();
#pragma unroll
  for (int it = 0; it < 2; ++it) {
    int row = (tid >> 4) + it * 16;          // 0..31
    int c8 = (tid & 15) << 3;                // 0..120
    bf16x8 v = *(const bf16x8*)(sh + row * 132 + c8);
    int gr = m0 + (row < 16 ? mi * 16 + row : 48 + mi * 16 + row);
    *(bf16x8*)(Out + (long long)gr * ldo + n0 + c8) = v;
  }
  __syncthreads();
}

// ---------------------------------------------------------------------------
// core4 (proj/final): 128x256 tile, 512 thr = 8 waves (2M x 4N), per-wave
// 64x64 (acc[4][4]). BK=32; 4 LDS buffers of 24 KiB; 3-deep global prefetch
// (vmcnt(6) certify); reg-dbuf fragments: tile kt+1's ds_reads issue after
// the certify barrier and drain under tile kt's 16 MFMA. 2 barriers/K-tile.
// 16B chunks swizzled c ^= (row>>1)&3, pre-swizzled global source, linear
// LDS dest. C[m,n] = sum_k A[m,k]*B[n,k], A/B bf16 K-fast. nkt even >= 4.
// ---------------------------------------------------------------------------
__device__ __forceinline__ void core4(
    const unsigned short* __restrict__ A, long long lda,
    const unsigned short* __restrict__ B, long long ldb,
    int nkt, f32x4 (&acc)[4][4], unsigned short* lds) {
  const int tid  = threadIdx.x;
  const int lane = tid & 63;
  const int w    = tid >> 6;
  const int wr   = w >> 2;            // 0..1
  const int wc   = w & 3;             // 0..3
  const int fr   = lane & 15;
  const int fq   = lane >> 4;
  const int csel = (fq ^ ((fr >> 1) & 3)) << 3;   // fragment chunk swizzle
  const int srow = tid >> 2;                      // staging row 0..127
  const int scsw = ((tid & 3) ^ ((srow >> 1) & 3)) << 3;
  const unsigned short* Asrc  = A + (long long)srow * lda + scsw;
  const unsigned short* Bsrc0 = B + (long long)srow * ldb + scsw;
  const unsigned short* Bsrc1 = B + (long long)(srow + 128) * ldb + scsw;
  unsigned short* dsta = lds + tid * 8;           // per-thread 16B slot

  auto stage = [&](int kt) {
    const int bo = (kt & 3) * 12288;
    const long long ko = (long long)kt * 32;
    __builtin_amdgcn_global_load_lds(AS1(Asrc + ko),  AS3(dsta + bo),        16, 0, 0);
    __builtin_amdgcn_global_load_lds(AS1(Bsrc0 + ko), AS3(dsta + bo + 4096), 16, 0, 0);
    __builtin_amdgcn_global_load_lds(AS1(Bsrc1 + ko), AS3(dsta + bo + 8192), 16, 0, 0);
  };
  auto rdfrag = [&](int kt, bf16x8 (&r)[8]) {
    const unsigned short* Ab = lds + (kt & 3) * 12288 + (wr * 64 + fr) * 32 + csel;
    const unsigned short* Bb = lds + (kt & 3) * 12288 + 4096 + (wc * 64 + fr) * 32 + csel;
#pragma unroll
    for (int mi = 0; mi < 4; ++mi) r[mi] = *(const bf16x8*)(Ab + mi * 512);
#pragma unroll
    for (int nj = 0; nj < 4; ++nj) r[4 + nj] = *(const bf16x8*)(Bb + nj * 512);
  };

  bf16x8 ra[8], rb[8];
  stage(0); stage(1); stage(2);
  asm volatile("s_waitcnt vmcnt(6)" ::: "memory");
  __builtin_amdgcn_s_barrier();
  rdfrag(0, ra);

  auto body = [&](int kt, bf16x8 (&cur)[8], bf16x8 (&nxt)[8]) {
    if (kt + 3 < nkt) {
      stage(kt + 3);
      asm volatile("s_waitcnt vmcnt(6)" ::: "memory");
    } else if (kt + 2 < nkt) {
      asm volatile("s_waitcnt vmcnt(3)" ::: "memory");
    } else if (kt + 1 < nkt) {
      asm volatile("s_waitcnt vmcnt(0)" ::: "memory");
    }
    if (kt + 1 < nkt) {
      __builtin_amdgcn_s_barrier();
      rdfrag(kt + 1, nxt);
    }
    __builtin_amdgcn_s_setprio(1);
#pragma unroll
    for (int mi = 0; mi < 4; ++mi)
#pragma unroll
      for (int nj = 0; nj < 4; ++nj)
        acc[mi][nj] = __builtin_amdgcn_mfma_f32_16x16x32_bf16(cur[mi], cur[4 + nj], acc[mi][nj], 0, 0, 0);
    __builtin_amdgcn_s_setprio(0);
    if (kt + 1 < nkt) __builtin_amdgcn_s_barrier();
  };

#pragma unroll 1
  for (int kt = 0; kt < nkt; kt += 2) {
    body(kt, ra, rb);
    body(kt + 1, rb, ra);
  }
}

// ---------------------------------------------------------------------------
// core4h (score/pv): core4 re-parameterized to 256 thr / 128x128 tile.
// 4 waves (2M x 2N), per-wave 64x64 (acc[4][4]). BK=32; 4 LDS buffers of
// 16 KiB = 64 KiB (-> 2 blocks/CU); stage = 4 global_load_lds (A 2, B 2);
// 3-deep prefetch, certify gates vmcnt(8)/(4)/(0); reg-dbuf fragments;
// 2 barriers/K-tile. nkt even >= 4.
// ---------------------------------------------------------------------------
__device__ __forceinline__ void core4h(
    const unsigned short* __restrict__ A, long long lda,
    const unsigned short* __restrict__ B, long long ldb,
    int nkt, f32x4 (&acc)[4][4], unsigned short* lds) {
  const int tid  = threadIdx.x;          // 0..255
  const int lane = tid & 63;
  const int w    = tid >> 6;             // 0..3
  const int wm   = (w & 1) << 6;         // M half
  const int wn   = (w >> 1) << 6;        // N half
  const int fr   = lane & 15;
  const int fq   = lane >> 4;
  const int csel = (fq ^ ((fr >> 1) & 3)) << 3;
  const int srow = tid >> 2;             // 0..63
  const int scsw = ((tid & 3) ^ ((srow >> 1) & 3)) << 3;
  const unsigned short* Asrc0 = A + (long long)srow * lda + scsw;
  const unsigned short* Asrc1 = A + (long long)(srow + 64) * lda + scsw;
  const unsigned short* Bsrc0 = B + (long long)srow * ldb + scsw;
  const unsigned short* Bsrc1 = B + (long long)(srow + 64) * ldb + scsw;
  unsigned short* dsta = lds + tid * 8;  // 16B per thread per instr

  auto stage = [&](int kt) {
    const int bo = (kt & 3) * 8192;
    const long long ko = (long long)kt * 32;
    __builtin_amdgcn_global_load_lds(AS1(Asrc0 + ko), AS3(dsta + bo),        16, 0, 0);
    __builtin_amdgcn_global_load_lds(AS1(Asrc1 + ko), AS3(dsta + bo + 2048), 16, 0, 0);
    __builtin_amdgcn_global_load_lds(AS1(Bsrc0 + ko), AS3(dsta + bo + 4096), 16, 0, 0);
    __builtin_amdgcn_global_load_lds(AS1(Bsrc1 + ko), AS3(dsta + bo + 6144), 16, 0, 0);
  };
  auto rdfrag = [&](int kt, bf16x8 (&r)[8]) {
    const unsigned short* Ab = lds + (kt & 3) * 8192 + (wm + fr) * 32 + csel;
    const unsigned short* Bb = lds + (kt & 3) * 8192 + 4096 + (wn + fr) * 32 + csel;
#pragma unroll
    for (int mi = 0; mi < 4; ++mi) r[mi] = *(const bf16x8*)(Ab + mi * 512);
#pragma unroll
    for (int nj = 0; nj < 4; ++nj) r[4 + nj] = *(const bf16x8*)(Bb + nj * 512);
  };

  bf16x8 ra[8], rb[8];
  stage(0); stage(1); stage(2);
  asm volatile("s_waitcnt vmcnt(8)" ::: "memory");
  __builtin_amdgcn_s_barrier();
  rdfrag(0, ra);

  auto body = [&](int kt, bf16x8 (&cur)[8], bf16x8 (&nxt)[8]) {
    if (kt + 3 < nkt) {
      stage(kt + 3);
      asm volatile("s_waitcnt vmcnt(8)" ::: "memory");
    } else if (kt + 2 < nkt) {
      asm volatile("s_waitcnt vmcnt(4)" ::: "memory");
    } else if (kt + 1 < nkt) {
      asm volatile("s_waitcnt vmcnt(0)" ::: "memory");
    }
    if (kt + 1 < nkt) {
      __builtin_amdgcn_s_barrier();
      rdfrag(kt + 1, nxt);
    }
    __builtin_amdgcn_s_setprio(1);
#pragma unroll
    for (int mi = 0; mi < 4; ++mi)
#pragma unroll
      for (int nj = 0; nj < 4; ++nj)
        acc[mi][nj] = __builtin_amdgcn_mfma_f32_16x16x32_bf16(cur[mi], cur[4 + nj], acc[mi][nj], 0, 0, 0);
    __builtin_amdgcn_s_setprio(0);
    if (kt + 1 < nkt) __builtin_amdgcn_s_barrier();
  };

#pragma unroll 1
  for (int kt = 0; kt < nkt; kt += 2) {
    body(kt, ra, rb);
    body(kt + 1, rb, ra);
  }
}

// ---- Q/K/V projections; Q/K get RoPE; V computed AS Vt (swapped operands) -
// R15: `which` is a kernel ARG (3 separate launches, grid (64,4) each) so
// each dispatch is individually visible in rocprof. Work mapping unchanged.
__global__ __launch_bounds__(512, 2) void proj_rope(
    const unsigned short* __restrict__ xb,
    const unsigned short* __restrict__ Wq, const unsigned short* __restrict__ Wk,
    const unsigned short* __restrict__ Wv,
    const float* __restrict__ bq, const float* __restrict__ bk, const float* __restrict__ bv,
    unsigned short* __restrict__ Q, unsigned short* __restrict__ Ko,
    unsigned short* __restrict__ Vt, const int which) {
  __shared__ unsigned short lds[49152];   // 96 KiB: GEMM 4-buf, then repack
  const int tid = threadIdx.x, lane = tid & 63, w = tid >> 6;
  const int wr = w >> 2, wc = w & 3;
  const int cl = lane & 15, q4 = lane >> 4;

  f32x4 acc[4][4];
#pragma unroll
  for (int i = 0; i < 4; i++)
#pragma unroll
    for (int j = 0; j < 4; j++)
#pragma unroll
      for (int k = 0; k < 4; k++) acc[i][j][k] = 0.0f;

  if (which == 2) {
    // ---- V path: Vt[d,s] = sum_k Wv[d,k] x[s,k]; A = Wv (m=d), B = x (n=s)
    const int p = blockIdx.x + 64 * blockIdx.y;     // physical 0..255
    const int m0 = ((p >> 3) & 7) * 128;            // d tile
    const int n0 = (4 * (p & 7) + (p >> 6)) * 256;  // global s tile (XCD remap)
    core4(Wv + (long long)m0 * 1024, 1024, xb + (long long)n0 * 1024, 1024, 32, acc, lds);
    __syncthreads();
    const int b = n0 >> 11, sloc = n0 & 2047;
#pragma unroll
    for (int mi = 0; mi < 4; ++mi) {
      const int lr = wr * 64 + mi * 16 + q4 * 4;
#pragma unroll
      for (int rr = 0; rr < 4; ++rr) {
        const float b_ = bv[m0 + lr + rr];          // bias per d-row
#pragma unroll
        for (int nj = 0; nj < 4; ++nj)
          lds[(lr + rr) * 264 + wc * 64 + nj * 16 + cl] = f2bf(acc[mi][nj][rr] + b_);
      }
    }
    __syncthreads();
    unsigned short* Outb = Vt + (long long)b * 1024 * 2048;
#pragma unroll
    for (int it = 0; it < 8; ++it) {
      int c = it * 512 + tid;
      int row = c >> 5, c8 = (c & 31) << 3;
      bf16x8 v = *(const bf16x8*)(lds + row * 264 + c8);
      *(bf16x8*)(Outb + (long long)(m0 + row) * 2048 + sloc + c8) = v;
    }
    return;
  }

  // ---- Q/K path: bias + RoPE (native sin/cos) ----
  const int m0 = blockIdx.x * 128;    // token rows
  const int n0 = blockIdx.y * 256;    // feature cols
  const unsigned short* W = which == 0 ? Wq : Wk;
  const float* bias = which == 0 ? bq : bk;
  unsigned short* Out = which == 0 ? Q : Ko;

  core4(xb + (long long)m0 * 1024, 1024, W + (long long)n0 * 1024, 1024, 32, acc, lds);
  __syncthreads();

  const float NEG_L2T_512 = -0.025952563239354392f;  // -log2(10000)/512
  const float INV2PI = 0.15915494309189535f;
  float freqn[4];
#pragma unroll
  for (int nj = 0; nj < 4; ++nj) {
    int gn = n0 + wc * 64 + nj * 16 + cl;
    freqn[nj] = exp2f(NEG_L2T_512 * (float)(gn >> 1));
  }
#pragma unroll
  for (int mi = 0; mi < 4; ++mi) {
    const int lr = wr * 64 + mi * 16 + q4 * 4;
    const int t0 = (m0 & 2047) + lr;   // batch-local time (tiles never straddle)
#pragma unroll
    for (int nj = 0; nj < 4; ++nj) {
      const int gn = n0 + wc * 64 + nj * 16 + cl;
      const float bi = bias[gn];
#pragma unroll
      for (int rr = 0; rr < 4; ++rr) {
        float v = acc[mi][nj][rr] + bi;
        float partner = __shfl_xor(v, 1, 64);
        float ang = (float)(t0 + rr) * freqn[nj];
        float rev = ang * INV2PI;
        rev = rev - floorf(rev);           // v_sin/v_cos domain
        float c_ = __builtin_amdgcn_cosf(rev);
        float s_ = __builtin_amdgcn_sinf(rev);
        v = v * c_ + ((gn & 1) ? partner : -partner) * s_;
        lds[(lr + rr) * 264 + wc * 64 + nj * 16 + cl] = f2bf(v);
      }
    }
  }
  __syncthreads();
#pragma unroll
  for (int it = 0; it < 8; ++it) {
    int c = it * 512 + tid;
    int row = c >> 5, c8 = (c & 31) << 3;
    bf16x8 v = *(const bf16x8*)(lds + row * 264 + c8);
    *(bf16x8*)(Out + (long long)(m0 + row) * 1024 + n0 + c8) = v;
  }
}

// ---- P = exp(Q K^T / sqrt(C)) (causal-zeroed), bf16; row sums via atomics -
__global__ __launch_bounds__(256, 2) void score_exp(const unsigned short* __restrict__ Q,
                                                    const unsigned short* __restrict__ Kk,
                                                    unsigned short* __restrict__ P,
                                                    float* __restrict__ row_sum) {
  __shared__ unsigned short sh[32768];   // 64 KiB: 4 GEMM bufs, then repack
  const int bx = blockIdx.x;
  int i = (int)((sqrtf(8.0f * (float)bx + 1.0f) - 1.0f) * 0.5f);
  while ((i + 1) * (i + 2) / 2 <= bx) ++i;
  while (i * (i + 1) / 2 > bx) --i;
  const int j = bx - i * (i + 1) / 2;       // 0..i
  const int b = blockIdx.z;
  const int m0 = i * 128, n0 = j * 128;
  const unsigned short* Qb = Q + (long long)b * 2048 * 1024;
  const unsigned short* Kb = Kk + (long long)b * 2048 * 1024;
  unsigned short* Pb = P + (long long)b * 2048 * 2048;
  float* rs = row_sum + b * 2048;

  f32x4 acc[4][4];
#pragma unroll
  for (int ii = 0; ii < 4; ii++)
#pragma unroll
    for (int jj = 0; jj < 4; jj++)
#pragma unroll
      for (int k = 0; k < 4; k++) acc[ii][jj][k] = 0.0f;

  core4h(Qb + (long long)m0 * 1024, 1024, Kb + (long long)n0 * 1024, 1024, 32, acc, sh);
  __syncthreads();

  const int tid = threadIdx.x, lane = tid & 63, w = tid >> 6;
  const int wm = (w & 1) << 6, wn = (w >> 1) << 6;
  const int cl = lane & 15, q4 = lane >> 4;
  const bool diag = (i == j);
#pragma unroll
  for (int mi = 0; mi < 4; mi++) {
    unsigned short vals[4][4];
    float rsum[4] = {0.f, 0.f, 0.f, 0.f};
#pragma unroll
    for (int ni = 0; ni < 4; ni++) {
      const int gn = n0 + wn + ni * 16 + cl;
#pragma unroll
      for (int rr = 0; rr < 4; rr++) {
        const int gm = m0 + wm + mi * 16 + q4 * 4 + rr;
        float e = (diag && gn > gm) ? 0.0f : __expf(acc[mi][ni][rr] * 0.03125f);
        vals[ni][rr] = f2bf(e);
        rsum[rr] += e;
      }
    }
#pragma unroll
    for (int rr = 0; rr < 4; rr++) {
#pragma unroll
      for (int off = 1; off < 16; off <<= 1) rsum[rr] += __shfl_xor(rsum[rr], off, 64);
    }
    if (cl == 0) {
      const int gm = m0 + wm + mi * 16 + q4 * 4;
#pragma unroll
      for (int rr = 0; rr < 4; rr++) atomicAdd(&rs[gm + rr], rsum[rr]);
    }
    repack_store_mi(vals, sh, mi, m0, n0, 2048, Pb);
  }
}

// ---- O = (P V) / row_sum; longest-K blocks dispatched first ---------------
__global__ __launch_bounds__(256, 2) void pv_gemm(const unsigned short* __restrict__ P,
                                                  const unsigned short* __restrict__ Vt,
                                                  const float* __restrict__ row_sum,
                                                  unsigned short* __restrict__ O) {
  __shared__ unsigned short sh[32768];   // 64 KiB: 4 GEMM bufs, then repack
  const int b = blockIdx.z;
  const int mt = 15 - blockIdx.x;   // longest K first (tail balance)
  const int m0 = mt * 128;          // t tile
  const int n0 = blockIdx.y * 128;  // d tile
  const unsigned short* Pb = P + (long long)b * 2048 * 2048;
  const unsigned short* Vb = Vt + (long long)b * 1024 * 2048;
  const float* rs = row_sum + b * 2048;
  const int nkt = 4 * (mt + 1);     // K = m0+128 -> K/32, even >= 4

  f32x4 acc[4][4];
#pragma unroll
  for (int i = 0; i < 4; i++)
#pragma unroll
    for (int j = 0; j < 4; j++)
#pragma unroll
      for (int k = 0; k < 4; k++) acc[i][j][k] = 0.0f;

  core4h(Pb + (long long)m0 * 2048, 2048, Vb + (long long)n0 * 2048, 2048, nkt, acc, sh);
  __syncthreads();

  const int tid = threadIdx.x, lane = tid & 63, w = tid >> 6;
  const int wm = (w & 1) << 6;
  const int q4 = lane >> 4;
#pragma unroll
  for (int mi = 0; mi < 4; mi++) {
    unsigned short vals[4][4];
    float inv[4];
    const int gm0 = m0 + wm + mi * 16 + q4 * 4;
#pragma unroll
    for (int rr = 0; rr < 4; rr++) inv[rr] = 1.0f / rs[gm0 + rr];
#pragma unroll
    for (int ni = 0; ni < 4; ni++)
#pragma unroll
      for (int rr = 0; rr < 4; rr++)
        vals[ni][rr] = f2bf(acc[mi][ni][rr] * inv[rr]);
    repack_store_mi(vals, sh, mi, m0, n0, 1024, O + (long long)b * 2048 * 1024);
  }
}

// ---- out = O Wf^T + bf, fp32 out (core4, 512 thr) -------------------------
__global__ __launch_bounds__(512, 2) void final_gemm(const unsigned short* __restrict__ O,
                                                     const unsigned short* __restrict__ Wf,
                                                     const float* __restrict__ bf_,
                                                     float* __restrict__ out) {
  __shared__ unsigned short lds[49152];
  float* shf = (float*)lds;
  const int tid = threadIdx.x, lane = tid & 63, w = tid >> 6;
  const int wr = w >> 2, wc = w & 3;
  const int cl = lane & 15, q4 = lane >> 4;
  const int m0 = blockIdx.x * 128;
  const int n0 = blockIdx.y * 256;

  f32x4 acc[4][4];
#pragma unroll
  for (int i = 0; i < 4; i++)
#pragma unroll
    for (int j = 0; j < 4; j++)
#pragma unroll
      for (int k = 0; k < 4; k++) acc[i][j][k] = 0.0f;

  core4(O + (long long)m0 * 1024, 1024, Wf + (long long)n0 * 1024, 1024, 32, acc, lds);

  // fp32 repack in two 64-row rounds (64 x 260 floats = 66.5 KB <= 96 KB)
#pragma unroll
  for (int r = 0; r < 2; ++r) {
    __syncthreads();
    if (wr == r) {
#pragma unroll
      for (int mi = 0; mi < 4; ++mi)
#pragma unroll
        for (int nj = 0; nj < 4; ++nj) {
          const int col = wc * 64 + nj * 16 + cl;
          const float bi = bf_[n0 + col];
#pragma unroll
          for (int rr = 0; rr < 4; ++rr)
            shf[(mi * 16 + q4 * 4 + rr) * 260 + col] = acc[mi][nj][rr] + bi;
        }
    }
    __syncthreads();
#pragma unroll
    for (int it = 0; it < 8; ++it) {
      int c = it * 512 + tid;
      int row = c >> 6, c4 = (c & 63) << 2;
      float4 v = *(const float4*)(shf + row * 260 + c4);
      *(float4*)(out + (long long)(m0 + r * 64 + row) * 1024 + n0 + c4) = v;
    }
  }
}

// ---------------------------------------------------------------------------
extern "C" void kernel_launch(void* const* d_in, const int* in_sizes, int n_in,
                              void* d_out, int out_size, void* d_ws, size_t ws_size,
                              hipStream_t stream) {
  (void)in_sizes; (void)n_in; (void)out_size; (void)ws_size;
  const float* x   = (const float*)d_in[0];
  const float* Wq  = (const float*)d_in[1];
  const float* bq  = (const float*)d_in[2];
  const float* Wk  = (const float*)d_in[3];
  const float* bk  = (const float*)d_in[4];
  const float* Wv  = (const float*)d_in[5];
  const float* bv  = (const float*)d_in[6];
  const float* Wf  = (const float*)d_in[7];
  const float* bf_ = (const float*)d_in[8];
  float* out = (float*)d_out;

  char* ws = (char*)d_ws;
  const size_t MB = 1024 * 1024;
  unsigned short* xb  = (unsigned short*)(ws);             // 16 MB
  unsigned short* Wqb = (unsigned short*)(ws + 16 * MB);   // 2 MB
  unsigned short* Wkb = (unsigned short*)(ws + 18 * MB);   // 2 MB
  unsigned short* Wvb = (unsigned short*)(ws + 20 * MB);   // 2 MB
  unsigned short* Wfb = (unsigned short*)(ws + 22 * MB);   // 2 MB
  unsigned short* Qb  = (unsigned short*)(ws + 24 * MB);   // 16 MB
  unsigned short* Kb  = (unsigned short*)(ws + 40 * MB);   // 16 MB
  unsigned short* Vtb = (unsigned short*)(ws + 56 * MB);   // 16 MB
  unsigned short* Ob  = (unsigned short*)(ws + 72 * MB);   // 16 MB
  unsigned short* Pb  = (unsigned short*)(ws + 88 * MB);   // 32 MB P bf16
  float*          rsum= (float*)(ws + 120 * MB);           // 32 KB row sums

  cast_all<<<dim3(3145728 / 256), dim3(256), 0, stream>>>(x, Wq, Wk, Wv, Wf, xb, Wqb, Wkb, Wvb, Wfb, rsum);
  proj_rope<<<dim3(64, 4), dim3(512), 0, stream>>>(xb, Wqb, Wkb, Wvb, bq, bk, bv, Qb, Kb, Vtb, 0);
  proj_rope<<<dim3(64, 4), dim3(512), 0, stream>>>(xb, Wqb, Wkb, Wvb, bq, bk, bv, Qb, Kb, Vtb, 1);
  proj_rope<<<dim3(64, 4), dim3(512), 0, stream>>>(xb, Wqb, Wkb, Wvb, bq, bk, bv, Qb, Kb, Vtb, 2);
  score_exp<<<dim3(136, 1, 4), dim3(256), 0, stream>>>(Qb, Kb, Pb, rsum);
  pv_gemm<<<dim3(16, 8, 4), dim3(256), 0, stream>>>(Pb, Vtb, rsum, Ob);
  final_gemm<<<dim3(64, 4), dim3(512), 0, stream>>>(Ob, Wfb, bf_, out);
}

// Round 8
// 280.211 us; speedup vs baseline: 1.1298x; 1.0323x over previous
//
#include <hip/hip_runtime.h>
#include <math.h>

// ---------------------------------------------------------------------------
// MultiChannelAttention on MI355X (gfx950)
// out = softmax(causal(rope(xWq^T) rope(xWk^T)^T / sqrt(C))) (xWv^T) Wf^T + b
// B=4 T=2048 C=1024. bf16 MFMA (16x16x32), fp32 accum.
// R16: counters convicted score_exp (47us, FETCH 103MB vs 32 compulsory,
//      occupancy ~1 blk/CU). Fixes: (a) core4h -> 3-buf LDS ring (48 KiB,
//      depth-2 prefetch, vmcnt(4) certify) = 3 blocks/CU; (b) score grid
//      flattened to 544 with XCD-chunked bijective remap (544=8*68) so each
//      XCD's triangle band (~5MB) fits its private L2. pv shares the core
//      changes. proj/final/cast untouched.
// R15: proj split into 3 launches (observability); rsum memset fused in cast.
// R11: core4 software pipeline (reg-dbuf fragments, counted vmcnt).
// R8: V projection computes Vt natively (A=Wv, B=x). R7: triangular score
//     grid; pv longest-K-first. R5: native v_sin/v_cos RoPE. R2: fused
//     exp-softmax (P=exp(s) bf16 + atomic row sums).
// Workspace layout (121 MB):
//   [0,16) xb  [16,24) Wq/Wk/Wv/Wf bf16  [24,40) Q  [40,56) K
//   [56,72) Vt  [72,88) O  [88,120) P bf16  [120,+32K) row_sum
// ---------------------------------------------------------------------------

#define AS1(p) ((__attribute__((address_space(1))) void*)(p))
#define AS3(p) ((__attribute__((address_space(3))) void*)(p))

typedef __attribute__((ext_vector_type(8))) short bf16x8;
typedef __attribute__((ext_vector_type(4))) float f32x4;

__device__ __forceinline__ unsigned short f2bf(float f) {
  unsigned int u = __float_as_uint(f);
  u += 0x7fffu + ((u >> 16) & 1u);   // round-to-nearest-even
  return (unsigned short)(u >> 16);
}

// ---- fp32 -> bf16 cast for x + 4 weight matrices, + rsum zero, one launch -
__global__ __launch_bounds__(256) void cast_all(
    const float* __restrict__ x, const float* __restrict__ Wq,
    const float* __restrict__ Wk, const float* __restrict__ Wv,
    const float* __restrict__ Wf,
    unsigned short* __restrict__ xb, unsigned short* __restrict__ Wqb,
    unsigned short* __restrict__ Wkb, unsigned short* __restrict__ Wvb,
    unsigned short* __restrict__ Wfb, float* __restrict__ rsum) {
  int i = blockIdx.x * 256 + threadIdx.x;           // float4 index
  if (i < 8192) rsum[i] = 0.0f;                     // fused memset (32 KB)
  const float* src; unsigned short* dst; int off;
  if (i < 2097152) { src = x; dst = xb; off = i; }
  else {
    int j = i - 2097152;
    int w = j >> 18; off = j & 262143;              // 262144 float4 per W
    src = (w == 0) ? Wq : (w == 1) ? Wk : (w == 2) ? Wv : Wf;
    dst = (w == 0) ? Wqb : (w == 1) ? Wkb : (w == 2) ? Wvb : Wfb;
  }
  float4 f = ((const float4*)src)[off];
  ushort4 o;
  o.x = f2bf(f.x); o.y = f2bf(f.y); o.z = f2bf(f.z); o.w = f2bf(f.w);
  ((ushort4*)dst)[off] = o;
}

// ---- LDS repack + coalesced bf16x8 store of one mi-slice (256 thr) --------
__device__ __forceinline__ void repack_store_mi(unsigned short (&vals)[4][4],
                                                unsigned short* sh, int mi,
                                                int m0, int n0, long long ldo,
                                                unsigned short* __restrict__ Out) {
  const int tid = threadIdx.x, lane = tid & 63, w = tid >> 6;
  const int half = w & 1, wn = (w >> 1) << 6;
  const int cl = lane & 15, q4 = lane >> 4;
  const int lr = half * 16 + q4 * 4;
#pragma unroll
  for (int ni = 0; ni < 4; ni++)
#pragma unroll
    for (int rr = 0; rr < 4; rr++)
      sh[(lr + rr) * 132 + wn + ni * 16 + cl] = vals[ni][rr];
  __syncthreads();
#pragma unroll
  for (int it = 0; it < 2; ++it) {
    int row = (tid >> 4) + it * 16;          // 0..31
    int c8 = (tid & 15) << 3;                // 0..120
    bf16x8 v = *(const bf16x8*)(sh + row * 132 + c8);
    int gr = m0 + (row < 16 ? mi * 16 + row : 48 + mi * 16 + row);
    *(bf16x8*)(Out + (long long)gr * ldo + n0 + c8) = v;
  }
  __syncthreads();
}

// ---------------------------------------------------------------------------
// core4 (proj/final): 128x256 tile, 512 thr = 8 waves (2M x 4N), per-wave
// 64x64 (acc[4][4]). BK=32; 4 LDS buffers of 24 KiB; 3-deep global prefetch
// (vmcnt(6) certify); reg-dbuf fragments. 2 barriers/K-tile. 16B chunks
// swizzled c ^= (row>>1)&3, pre-swizzled global source, linear LDS dest.
// C[m,n] = sum_k A[m,k]*B[n,k], A/B bf16 K-fast. nkt even >= 4.
// ---------------------------------------------------------------------------
__device__ __forceinline__ void core4(
    const unsigned short* __restrict__ A, long long lda,
    const unsigned short* __restrict__ B, long long ldb,
    int nkt, f32x4 (&acc)[4][4], unsigned short* lds) {
  const int tid  = threadIdx.x;
  const int lane = tid & 63;
  const int w    = tid >> 6;
  const int wr   = w >> 2;            // 0..1
  const int wc   = w & 3;             // 0..3
  const int fr   = lane & 15;
  const int fq   = lane >> 4;
  const int csel = (fq ^ ((fr >> 1) & 3)) << 3;   // fragment chunk swizzle
  const int srow = tid >> 2;                      // staging row 0..127
  const int scsw = ((tid & 3) ^ ((srow >> 1) & 3)) << 3;
  const unsigned short* Asrc  = A + (long long)srow * lda + scsw;
  const unsigned short* Bsrc0 = B + (long long)srow * ldb + scsw;
  const unsigned short* Bsrc1 = B + (long long)(srow + 128) * ldb + scsw;
  unsigned short* dsta = lds + tid * 8;           // per-thread 16B slot

  auto stage = [&](int kt) {
    const int bo = (kt & 3) * 12288;
    const long long ko = (long long)kt * 32;
    __builtin_amdgcn_global_load_lds(AS1(Asrc + ko),  AS3(dsta + bo),        16, 0, 0);
    __builtin_amdgcn_global_load_lds(AS1(Bsrc0 + ko), AS3(dsta + bo + 4096), 16, 0, 0);
    __builtin_amdgcn_global_load_lds(AS1(Bsrc1 + ko), AS3(dsta + bo + 8192), 16, 0, 0);
  };
  auto rdfrag = [&](int kt, bf16x8 (&r)[8]) {
    const unsigned short* Ab = lds + (kt & 3) * 12288 + (wr * 64 + fr) * 32 + csel;
    const unsigned short* Bb = lds + (kt & 3) * 12288 + 4096 + (wc * 64 + fr) * 32 + csel;
#pragma unroll
    for (int mi = 0; mi < 4; ++mi) r[mi] = *(const bf16x8*)(Ab + mi * 512);
#pragma unroll
    for (int nj = 0; nj < 4; ++nj) r[4 + nj] = *(const bf16x8*)(Bb + nj * 512);
  };

  bf16x8 ra[8], rb[8];
  stage(0); stage(1); stage(2);
  asm volatile("s_waitcnt vmcnt(6)" ::: "memory");
  __builtin_amdgcn_s_barrier();
  rdfrag(0, ra);

  auto body = [&](int kt, bf16x8 (&cur)[8], bf16x8 (&nxt)[8]) {
    if (kt + 3 < nkt) {
      stage(kt + 3);
      asm volatile("s_waitcnt vmcnt(6)" ::: "memory");
    } else if (kt + 2 < nkt) {
      asm volatile("s_waitcnt vmcnt(3)" ::: "memory");
    } else if (kt + 1 < nkt) {
      asm volatile("s_waitcnt vmcnt(0)" ::: "memory");
    }
    if (kt + 1 < nkt) {
      __builtin_amdgcn_s_barrier();
      rdfrag(kt + 1, nxt);
    }
    __builtin_amdgcn_s_setprio(1);
#pragma unroll
    for (int mi = 0; mi < 4; ++mi)
#pragma unroll
      for (int nj = 0; nj < 4; ++nj)
        acc[mi][nj] = __builtin_amdgcn_mfma_f32_16x16x32_bf16(cur[mi], cur[4 + nj], acc[mi][nj], 0, 0, 0);
    __builtin_amdgcn_s_setprio(0);
    if (kt + 1 < nkt) __builtin_amdgcn_s_barrier();
  };

#pragma unroll 1
  for (int kt = 0; kt < nkt; kt += 2) {
    body(kt, ra, rb);
    body(kt + 1, rb, ra);
  }
}

// ---------------------------------------------------------------------------
// core4h (score/pv): 256 thr / 128x128 tile, 4 waves (2M x 2N), per-wave
// 64x64 (acc[4][4]). BK=32; R16: 3 LDS buffers of 16 KiB = 48 KiB
// -> 3 blocks/CU (144 <= 160 KiB). Depth-2 prefetch: stage(kt+2) in body,
// gate vmcnt(4) certifies tile kt+1 (kt+2's 4 loads stay in flight).
// Reg-dbuf fragments; 2 barriers/K-tile. WAR ledger: stage(kt+2) overwrites
// buf[(kt-1)%3], whose rdfrag(kt-1) reads were consumed by MFMA at iter kt-1
// before its trailing barrier. nkt even >= 2.
// ---------------------------------------------------------------------------
__device__ __forceinline__ void core4h(
    const unsigned short* __restrict__ A, long long lda,
    const unsigned short* __restrict__ B, long long ldb,
    int nkt, f32x4 (&acc)[4][4], unsigned short* lds) {
  const int tid  = threadIdx.x;          // 0..255
  const int lane = tid & 63;
  const int w    = tid >> 6;             // 0..3
  const int wm   = (w & 1) << 6;         // M half
  const int wn   = (w >> 1) << 6;        // N half
  const int fr   = lane & 15;
  const int fq   = lane >> 4;
  const int csel = (fq ^ ((fr >> 1) & 3)) << 3;
  const int srow = tid >> 2;             // 0..63
  const int scsw = ((tid & 3) ^ ((srow >> 1) & 3)) << 3;
  const unsigned short* Asrc0 = A + (long long)srow * lda + scsw;
  const unsigned short* Asrc1 = A + (long long)(srow + 64) * lda + scsw;
  const unsigned short* Bsrc0 = B + (long long)srow * ldb + scsw;
  const unsigned short* Bsrc1 = B + (long long)(srow + 64) * ldb + scsw;
  unsigned short* dsta = lds + tid * 8;  // 16B per thread per instr

  auto stage = [&](int kt) {
    const int bo = (kt % 3) * 8192;
    const long long ko = (long long)kt * 32;
    __builtin_amdgcn_global_load_lds(AS1(Asrc0 + ko), AS3(dsta + bo),        16, 0, 0);
    __builtin_amdgcn_global_load_lds(AS1(Asrc1 + ko), AS3(dsta + bo + 2048), 16, 0, 0);
    __builtin_amdgcn_global_load_lds(AS1(Bsrc0 + ko), AS3(dsta + bo + 4096), 16, 0, 0);
    __builtin_amdgcn_global_load_lds(AS1(Bsrc1 + ko), AS3(dsta + bo + 6144), 16, 0, 0);
  };
  auto rdfrag = [&](int kt, bf16x8 (&r)[8]) {
    const unsigned short* Ab = lds + (kt % 3) * 8192 + (wm + fr) * 32 + csel;
    const unsigned short* Bb = lds + (kt % 3) * 8192 + 4096 + (wn + fr) * 32 + csel;
#pragma unroll
    for (int mi = 0; mi < 4; ++mi) r[mi] = *(const bf16x8*)(Ab + mi * 512);
#pragma unroll
    for (int nj = 0; nj < 4; ++nj) r[4 + nj] = *(const bf16x8*)(Bb + nj * 512);
  };

  bf16x8 ra[8], rb[8];
  stage(0); stage(1);
  asm volatile("s_waitcnt vmcnt(4)" ::: "memory");   // tile 0 landed
  __builtin_amdgcn_s_barrier();
  rdfrag(0, ra);

  auto body = [&](int kt, bf16x8 (&cur)[8], bf16x8 (&nxt)[8]) {
    if (kt + 2 < nkt) {
      stage(kt + 2);
      asm volatile("s_waitcnt vmcnt(4)" ::: "memory");   // tile kt+1 landed
    } else if (kt + 1 < nkt) {
      asm volatile("s_waitcnt vmcnt(0)" ::: "memory");
    }
    if (kt + 1 < nkt) {
      __builtin_amdgcn_s_barrier();
      rdfrag(kt + 1, nxt);
    }
    __builtin_amdgcn_s_setprio(1);
#pragma unroll
    for (int mi = 0; mi < 4; ++mi)
#pragma unroll
      for (int nj = 0; nj < 4; ++nj)
        acc[mi][nj] = __builtin_amdgcn_mfma_f32_16x16x32_bf16(cur[mi], cur[4 + nj], acc[mi][nj], 0, 0, 0);
    __builtin_amdgcn_s_setprio(0);
    if (kt + 1 < nkt) __builtin_amdgcn_s_barrier();
  };

#pragma unroll 1
  for (int kt = 0; kt < nkt; kt += 2) {
    body(kt, ra, rb);
    body(kt + 1, rb, ra);
  }
}

// ---- Q/K/V projections; Q/K get RoPE; V computed AS Vt (swapped operands) -
// `which` is a kernel ARG (3 launches, grid (64,4) each).
__global__ __launch_bounds__(512, 2) void proj_rope(
    const unsigned short* __restrict__ xb,
    const unsigned short* __restrict__ Wq, const unsigned short* __restrict__ Wk,
    const unsigned short* __restrict__ Wv,
    const float* __restrict__ bq, const float* __restrict__ bk, const float* __restrict__ bv,
    unsigned short* __restrict__ Q, unsigned short* __restrict__ Ko,
    unsigned short* __restrict__ Vt, const int which) {
  __shared__ unsigned short lds[49152];   // 96 KiB: GEMM 4-buf, then repack
  const int tid = threadIdx.x, lane = tid & 63, w = tid >> 6;
  const int wr = w >> 2, wc = w & 3;
  const int cl = lane & 15, q4 = lane >> 4;

  f32x4 acc[4][4];
#pragma unroll
  for (int i = 0; i < 4; i++)
#pragma unroll
    for (int j = 0; j < 4; j++)
#pragma unroll
      for (int k = 0; k < 4; k++) acc[i][j][k] = 0.0f;

  if (which == 2) {
    // ---- V path: Vt[d,s] = sum_k Wv[d,k] x[s,k]; A = Wv (m=d), B = x (n=s)
    const int p = blockIdx.x + 64 * blockIdx.y;     // physical 0..255
    const int m0 = ((p >> 3) & 7) * 128;            // d tile
    const int n0 = (4 * (p & 7) + (p >> 6)) * 256;  // global s tile (XCD remap)
    core4(Wv + (long long)m0 * 1024, 1024, xb + (long long)n0 * 1024, 1024, 32, acc, lds);
    __syncthreads();
    const int b = n0 >> 11, sloc = n0 & 2047;
#pragma unroll
    for (int mi = 0; mi < 4; ++mi) {
      const int lr = wr * 64 + mi * 16 + q4 * 4;
#pragma unroll
      for (int rr = 0; rr < 4; ++rr) {
        const float b_ = bv[m0 + lr + rr];          // bias per d-row
#pragma unroll
        for (int nj = 0; nj < 4; ++nj)
          lds[(lr + rr) * 264 + wc * 64 + nj * 16 + cl] = f2bf(acc[mi][nj][rr] + b_);
      }
    }
    __syncthreads();
    unsigned short* Outb = Vt + (long long)b * 1024 * 2048;
#pragma unroll
    for (int it = 0; it < 8; ++it) {
      int c = it * 512 + tid;
      int row = c >> 5, c8 = (c & 31) << 3;
      bf16x8 v = *(const bf16x8*)(lds + row * 264 + c8);
      *(bf16x8*)(Outb + (long long)(m0 + row) * 2048 + sloc + c8) = v;
    }
    return;
  }

  // ---- Q/K path: bias + RoPE (native sin/cos) ----
  const int m0 = blockIdx.x * 128;    // token rows
  const int n0 = blockIdx.y * 256;    // feature cols
  const unsigned short* W = which == 0 ? Wq : Wk;
  const float* bias = which == 0 ? bq : bk;
  unsigned short* Out = which == 0 ? Q : Ko;

  core4(xb + (long long)m0 * 1024, 1024, W + (long long)n0 * 1024, 1024, 32, acc, lds);
  __syncthreads();

  const float NEG_L2T_512 = -0.025952563239354392f;  // -log2(10000)/512
  const float INV2PI = 0.15915494309189535f;
  float freqn[4];
#pragma unroll
  for (int nj = 0; nj < 4; ++nj) {
    int gn = n0 + wc * 64 + nj * 16 + cl;
    freqn[nj] = exp2f(NEG_L2T_512 * (float)(gn >> 1));
  }
#pragma unroll
  for (int mi = 0; mi < 4; ++mi) {
    const int lr = wr * 64 + mi * 16 + q4 * 4;
    const int t0 = (m0 & 2047) + lr;   // batch-local time (tiles never straddle)
#pragma unroll
    for (int nj = 0; nj < 4; ++nj) {
      const int gn = n0 + wc * 64 + nj * 16 + cl;
      const float bi = bias[gn];
#pragma unroll
      for (int rr = 0; rr < 4; ++rr) {
        float v = acc[mi][nj][rr] + bi;
        float partner = __shfl_xor(v, 1, 64);
        float ang = (float)(t0 + rr) * freqn[nj];
        float rev = ang * INV2PI;
        rev = rev - floorf(rev);           // v_sin/v_cos domain
        float c_ = __builtin_amdgcn_cosf(rev);
        float s_ = __builtin_amdgcn_sinf(rev);
        v = v * c_ + ((gn & 1) ? partner : -partner) * s_;
        lds[(lr + rr) * 264 + wc * 64 + nj * 16 + cl] = f2bf(v);
      }
    }
  }
  __syncthreads();
#pragma unroll
  for (int it = 0; it < 8; ++it) {
    int c = it * 512 + tid;
    int row = c >> 5, c8 = (c & 31) << 3;
    bf16x8 v = *(const bf16x8*)(lds + row * 264 + c8);
    *(bf16x8*)(Out + (long long)(m0 + row) * 1024 + n0 + c8) = v;
  }
}

// ---- P = exp(Q K^T / sqrt(C)) (causal-zeroed), bf16; row sums via atomics -
// R16: flat 544-block grid, XCD-chunked bijective remap (544 = 8*68) so each
// XCD owns a contiguous (b, triangle) band -> Q/K panels L2-resident.
__global__ __launch_bounds__(256, 2) void score_exp(const unsigned short* __restrict__ Q,
                                                    const unsigned short* __restrict__ Kk,
                                                    unsigned short* __restrict__ P,
                                                    float* __restrict__ row_sum) {
  __shared__ unsigned short sh[24576];   // 48 KiB: 3 GEMM bufs, then repack
  const int flat = blockIdx.x;                       // 0..543
  const int swz = (flat & 7) * 68 + (flat >> 3);     // bijective XCD chunking
  const int b = swz / 136;
  const int bx = swz % 136;
  int i = (int)((sqrtf(8.0f * (float)bx + 1.0f) - 1.0f) * 0.5f);
  while ((i + 1) * (i + 2) / 2 <= bx) ++i;
  while (i * (i + 1) / 2 > bx) --i;
  const int j = bx - i * (i + 1) / 2;       // 0..i
  const int m0 = i * 128, n0 = j * 128;
  const unsigned short* Qb = Q + (long long)b * 2048 * 1024;
  const unsigned short* Kb = Kk + (long long)b * 2048 * 1024;
  unsigned short* Pb = P + (long long)b * 2048 * 2048;
  float* rs = row_sum + b * 2048;

  f32x4 acc[4][4];
#pragma unroll
  for (int ii = 0; ii < 4; ii++)
#pragma unroll
    for (int jj = 0; jj < 4; jj++)
#pragma unroll
      for (int k = 0; k < 4; k++) acc[ii][jj][k] = 0.0f;

  core4h(Qb + (long long)m0 * 1024, 1024, Kb + (long long)n0 * 1024, 1024, 32, acc, sh);
  __syncthreads();

  const int tid = threadIdx.x, lane = tid & 63, w = tid >> 6;
  const int wm = (w & 1) << 6, wn = (w >> 1) << 6;
  const int cl = lane & 15, q4 = lane >> 4;
  const bool diag = (i == j);
#pragma unroll
  for (int mi = 0; mi < 4; mi++) {
    unsigned short vals[4][4];
    float rsum[4] = {0.f, 0.f, 0.f, 0.f};
#pragma unroll
    for (int ni = 0; ni < 4; ni++) {
      const int gn = n0 + wn + ni * 16 + cl;
#pragma unroll
      for (int rr = 0; rr < 4; rr++) {
        const int gm = m0 + wm + mi * 16 + q4 * 4 + rr;
        float e = (diag && gn > gm) ? 0.0f : __expf(acc[mi][ni][rr] * 0.03125f);
        vals[ni][rr] = f2bf(e);
        rsum[rr] += e;
      }
    }
#pragma unroll
    for (int rr = 0; rr < 4; rr++) {
#pragma unroll
      for (int off = 1; off < 16; off <<= 1) rsum[rr] += __shfl_xor(rsum[rr], off, 64);
    }
    if (cl == 0) {
      const int gm = m0 + wm + mi * 16 + q4 * 4;
#pragma unroll
      for (int rr = 0; rr < 4; rr++) atomicAdd(&rs[gm + rr], rsum[rr]);
    }
    repack_store_mi(vals, sh, mi, m0, n0, 2048, Pb);
  }
}

// ---- O = (P V) / row_sum; longest-K blocks dispatched first ---------------
__global__ __launch_bounds__(256, 2) void pv_gemm(const unsigned short* __restrict__ P,
                                                  const unsigned short* __restrict__ Vt,
                                                  const float* __restrict__ row_sum,
                                                  unsigned short* __restrict__ O) {
  __shared__ unsigned short sh[24576];   // 48 KiB: 3 GEMM bufs, then repack
  const int b = blockIdx.z;
  const int mt = 15 - blockIdx.x;   // longest K first (tail balance)
  const int m0 = mt * 128;          // t tile
  const int n0 = blockIdx.y * 128;  // d tile
  const unsigned short* Pb = P + (long long)b * 2048 * 2048;
  const unsigned short* Vb = Vt + (long long)b * 1024 * 2048;
  const float* rs = row_sum + b * 2048;
  const int nkt = 4 * (mt + 1);     // K = m0+128 -> K/32, even >= 4

  f32x4 acc[4][4];
#pragma unroll
  for (int i = 0; i < 4; i++)
#pragma unroll
    for (int j = 0; j < 4; j++)
#pragma unroll
      for (int k = 0; k < 4; k++) acc[i][j][k] = 0.0f;

  core4h(Pb + (long long)m0 * 2048, 2048, Vb + (long long)n0 * 2048, 2048, nkt, acc, sh);
  __syncthreads();

  const int tid = threadIdx.x, lane = tid & 63, w = tid >> 6;
  const int wm = (w & 1) << 6;
  const int q4 = lane >> 4;
#pragma unroll
  for (int mi = 0; mi < 4; mi++) {
    unsigned short vals[4][4];
    float inv[4];
    const int gm0 = m0 + wm + mi * 16 + q4 * 4;
#pragma unroll
    for (int rr = 0; rr < 4; rr++) inv[rr] = 1.0f / rs[gm0 + rr];
#pragma unroll
    for (int ni = 0; ni < 4; ni++)
#pragma unroll
      for (int rr = 0; rr < 4; rr++)
        vals[ni][rr] = f2bf(acc[mi][ni][rr] * inv[rr]);
    repack_store_mi(vals, sh, mi, m0, n0, 1024, O + (long long)b * 2048 * 1024);
  }
}

// ---- out = O Wf^T + bf, fp32 out (core4, 512 thr) -------------------------
__global__ __launch_bounds__(512, 2) void final_gemm(const unsigned short* __restrict__ O,
                                                     const unsigned short* __restrict__ Wf,
                                                     const float* __restrict__ bf_,
                                                     float* __restrict__ out) {
  __shared__ unsigned short lds[49152];
  float* shf = (float*)lds;
  const int tid = threadIdx.x, lane = tid & 63, w = tid >> 6;
  const int wr = w >> 2, wc = w & 3;
  const int cl = lane & 15, q4 = lane >> 4;
  const int m0 = blockIdx.x * 128;
  const int n0 = blockIdx.y * 256;

  f32x4 acc[4][4];
#pragma unroll
  for (int i = 0; i < 4; i++)
#pragma unroll
    for (int j = 0; j < 4; j++)
#pragma unroll
      for (int k = 0; k < 4; k++) acc[i][j][k] = 0.0f;

  core4(O + (long long)m0 * 1024, 1024, Wf + (long long)n0 * 1024, 1024, 32, acc, lds);

  // fp32 repack in two 64-row rounds (64 x 260 floats = 66.5 KB <= 96 KB)
#pragma unroll
  for (int r = 0; r < 2; ++r) {
    __syncthreads();
    if (wr == r) {
#pragma unroll
      for (int mi = 0; mi < 4; ++mi)
#pragma unroll
        for (int nj = 0; nj < 4; ++nj) {
          const int col = wc * 64 + nj * 16 + cl;
          const float bi = bf_[n0 + col];
#pragma unroll
          for (int rr = 0; rr < 4; ++rr)
            shf[(mi * 16 + q4 * 4 + rr) * 260 + col] = acc[mi][nj][rr] + bi;
        }
    }
    __syncthreads();
#pragma unroll
    for (int it = 0; it < 8; ++it) {
      int c = it * 512 + tid;
      int row = c >> 6, c4 = (c & 63) << 2;
      float4 v = *(const float4*)(shf + row * 260 + c4);
      *(float4*)(out + (long long)(m0 + r * 64 + row) * 1024 + n0 + c4) = v;
    }
  }
}

// ---------------------------------------------------------------------------
extern "C" void kernel_launch(void* const* d_in, const int* in_sizes, int n_in,
                              void* d_out, int out_size, void* d_ws, size_t ws_size,
                              hipStream_t stream) {
  (void)in_sizes; (void)n_in; (void)out_size; (void)ws_size;
  const float* x   = (const float*)d_in[0];
  const float* Wq  = (const float*)d_in[1];
  const float* bq  = (const float*)d_in[2];
  const float* Wk  = (const float*)d_in[3];
  const float* bk  = (const float*)d_in[4];
  const float* Wv  = (const float*)d_in[5];
  const float* bv  = (const float*)d_in[6];
  const float* Wf  = (const float*)d_in[7];
  const float* bf_ = (const float*)d_in[8];
  float* out = (float*)d_out;

  char* ws = (char*)d_ws;
  const size_t MB = 1024 * 1024;
  unsigned short* xb  = (unsigned short*)(ws);             // 16 MB
  unsigned short* Wqb = (unsigned short*)(ws + 16 * MB);   // 2 MB
  unsigned short* Wkb = (unsigned short*)(ws + 18 * MB);   // 2 MB
  unsigned short* Wvb = (unsigned short*)(ws + 20 * MB);   // 2 MB
  unsigned short* Wfb = (unsigned short*)(ws + 22 * MB);   // 2 MB
  unsigned short* Qb  = (unsigned short*)(ws + 24 * MB);   // 16 MB
  unsigned short* Kb  = (unsigned short*)(ws + 40 * MB);   // 16 MB
  unsigned short* Vtb = (unsigned short*)(ws + 56 * MB);   // 16 MB
  unsigned short* Ob  = (unsigned short*)(ws + 72 * MB);   // 16 MB
  unsigned short* Pb  = (unsigned short*)(ws + 88 * MB);   // 32 MB P bf16
  float*          rsum= (float*)(ws + 120 * MB);           // 32 KB row sums

  cast_all<<<dim3(3145728 / 256), dim3(256), 0, stream>>>(x, Wq, Wk, Wv, Wf, xb, Wqb, Wkb, Wvb, Wfb, rsum);
  proj_rope<<<dim3(64, 4), dim3(512), 0, stream>>>(xb, Wqb, Wkb, Wvb, bq, bk, bv, Qb, Kb, Vtb, 0);
  proj_rope<<<dim3(64, 4), dim3(512), 0, stream>>>(xb, Wqb, Wkb, Wvb, bq, bk, bv, Qb, Kb, Vtb, 1);
  proj_rope<<<dim3(64, 4), dim3(512), 0, stream>>>(xb, Wqb, Wkb, Wvb, bq, bk, bv, Qb, Kb, Vtb, 2);
  score_exp<<<dim3(544), dim3(256), 0, stream>>>(Qb, Kb, Pb, rsum);
  pv_gemm<<<dim3(16, 8, 4), dim3(256), 0, stream>>>(Pb, Vtb, rsum, Ob);
  final_gemm<<<dim3(64, 4), dim3(512), 0, stream>>>(Ob, Wfb, bf_, out);
}

// Round 9
// 271.010 us; speedup vs baseline: 1.1682x; 1.0339x over previous
//
#include <hip/hip_runtime.h>
#include <math.h>

// ---------------------------------------------------------------------------
// MultiChannelAttention on MI355X (gfx950)
// out = softmax(causal(rope(xWq^T) rope(xWk^T)^T / sqrt(C))) (xWv^T) Wf^T + b
// B=4 T=2048 C=1024. bf16 MFMA (16x16x32), fp32 accum.
// R17: pv_gemm grid -> flat 512 with XCD-paired balanced decode:
//      xcd=p&7; groups pair mt=15-xcd with mt=xcd (per-CU work exactly 68
//      K-tiles: one long + one short block); all 8 d-tiles of a (b,mt)
//      group contiguous on one XCD -> P panel L2-resident, 8x reuse.
//      Counters: pv was 46.6us, FETCH 60MB, occupancy 10.6% (tail drain +
//      scattered P traffic). Everything else unchanged from R16.
// R16: score 3-buf ring (48KiB, 3 blk/CU) + XCD-chunked score grid. 280.2us.
// R15: proj split into 3 launches (observability); rsum memset in cast.
// R11: core4 software pipeline (reg-dbuf fragments, counted vmcnt).
// R8: V projection computes Vt natively. R7: triangular score grid.
// R5: native v_sin/v_cos RoPE. R2: fused exp-softmax (P=exp(s), atomics).
// Workspace layout (121 MB):
//   [0,16) xb  [16,24) Wq/Wk/Wv/Wf bf16  [24,40) Q  [40,56) K
//   [56,72) Vt  [72,88) O  [88,120) P bf16  [120,+32K) row_sum
// ---------------------------------------------------------------------------

#define AS1(p) ((__attribute__((address_space(1))) void*)(p))
#define AS3(p) ((__attribute__((address_space(3))) void*)(p))

typedef __attribute__((ext_vector_type(8))) short bf16x8;
typedef __attribute__((ext_vector_type(4))) float f32x4;

__device__ __forceinline__ unsigned short f2bf(float f) {
  unsigned int u = __float_as_uint(f);
  u += 0x7fffu + ((u >> 16) & 1u);   // round-to-nearest-even
  return (unsigned short)(u >> 16);
}

// ---- fp32 -> bf16 cast for x + 4 weight matrices, + rsum zero, one launch -
__global__ __launch_bounds__(256) void cast_all(
    const float* __restrict__ x, const float* __restrict__ Wq,
    const float* __restrict__ Wk, const float* __restrict__ Wv,
    const float* __restrict__ Wf,
    unsigned short* __restrict__ xb, unsigned short* __restrict__ Wqb,
    unsigned short* __restrict__ Wkb, unsigned short* __restrict__ Wvb,
    unsigned short* __restrict__ Wfb, float* __restrict__ rsum) {
  int i = blockIdx.x * 256 + threadIdx.x;           // float4 index
  if (i < 8192) rsum[i] = 0.0f;                     // fused memset (32 KB)
  const float* src; unsigned short* dst; int off;
  if (i < 2097152) { src = x; dst = xb; off = i; }
  else {
    int j = i - 2097152;
    int w = j >> 18; off = j & 262143;              // 262144 float4 per W
    src = (w == 0) ? Wq : (w == 1) ? Wk : (w == 2) ? Wv : Wf;
    dst = (w == 0) ? Wqb : (w == 1) ? Wkb : (w == 2) ? Wvb : Wfb;
  }
  float4 f = ((const float4*)src)[off];
  ushort4 o;
  o.x = f2bf(f.x); o.y = f2bf(f.y); o.z = f2bf(f.z); o.w = f2bf(f.w);
  ((ushort4*)dst)[off] = o;
}

// ---- LDS repack + coalesced bf16x8 store of one mi-slice (256 thr) --------
__device__ __forceinline__ void repack_store_mi(unsigned short (&vals)[4][4],
                                                unsigned short* sh, int mi,
                                                int m0, int n0, long long ldo,
                                                unsigned short* __restrict__ Out) {
  const int tid = threadIdx.x, lane = tid & 63, w = tid >> 6;
  const int half = w & 1, wn = (w >> 1) << 6;
  const int cl = lane & 15, q4 = lane >> 4;
  const int lr = half * 16 + q4 * 4;
#pragma unroll
  for (int ni = 0; ni < 4; ni++)
#pragma unroll
    for (int rr = 0; rr < 4; rr++)
      sh[(lr + rr) * 132 + wn + ni * 16 + cl] = vals[ni][rr];
  __syncthreads();
#pragma unroll
  for (int it = 0; it < 2; ++it) {
    int row = (tid >> 4) + it * 16;          // 0..31
    int c8 = (tid & 15) << 3;                // 0..120
    bf16x8 v = *(const bf16x8*)(sh + row * 132 + c8);
    int gr = m0 + (row < 16 ? mi * 16 + row : 48 + mi * 16 + row);
    *(bf16x8*)(Out + (long long)gr * ldo + n0 + c8) = v;
  }
  __syncthreads();
}

// ---------------------------------------------------------------------------
// core4 (proj/final): 128x256 tile, 512 thr = 8 waves (2M x 4N), per-wave
// 64x64 (acc[4][4]). BK=32; 4 LDS buffers of 24 KiB; 3-deep global prefetch
// (vmcnt(6) certify); reg-dbuf fragments. 2 barriers/K-tile. 16B chunks
// swizzled c ^= (row>>1)&3, pre-swizzled global source, linear LDS dest.
// C[m,n] = sum_k A[m,k]*B[n,k], A/B bf16 K-fast. nkt even >= 4.
// ---------------------------------------------------------------------------
__device__ __forceinline__ void core4(
    const unsigned short* __restrict__ A, long long lda,
    const unsigned short* __restrict__ B, long long ldb,
    int nkt, f32x4 (&acc)[4][4], unsigned short* lds) {
  const int tid  = threadIdx.x;
  const int lane = tid & 63;
  const int w    = tid >> 6;
  const int wr   = w >> 2;            // 0..1
  const int wc   = w & 3;             // 0..3
  const int fr   = lane & 15;
  const int fq   = lane >> 4;
  const int csel = (fq ^ ((fr >> 1) & 3)) << 3;   // fragment chunk swizzle
  const int srow = tid >> 2;                      // staging row 0..127
  const int scsw = ((tid & 3) ^ ((srow >> 1) & 3)) << 3;
  const unsigned short* Asrc  = A + (long long)srow * lda + scsw;
  const unsigned short* Bsrc0 = B + (long long)srow * ldb + scsw;
  const unsigned short* Bsrc1 = B + (long long)(srow + 128) * ldb + scsw;
  unsigned short* dsta = lds + tid * 8;           // per-thread 16B slot

  auto stage = [&](int kt) {
    const int bo = (kt & 3) * 12288;
    const long long ko = (long long)kt * 32;
    __builtin_amdgcn_global_load_lds(AS1(Asrc + ko),  AS3(dsta + bo),        16, 0, 0);
    __builtin_amdgcn_global_load_lds(AS1(Bsrc0 + ko), AS3(dsta + bo + 4096), 16, 0, 0);
    __builtin_amdgcn_global_load_lds(AS1(Bsrc1 + ko), AS3(dsta + bo + 8192), 16, 0, 0);
  };
  auto rdfrag = [&](int kt, bf16x8 (&r)[8]) {
    const unsigned short* Ab = lds + (kt & 3) * 12288 + (wr * 64 + fr) * 32 + csel;
    const unsigned short* Bb = lds + (kt & 3) * 12288 + 4096 + (wc * 64 + fr) * 32 + csel;
#pragma unroll
    for (int mi = 0; mi < 4; ++mi) r[mi] = *(const bf16x8*)(Ab + mi * 512);
#pragma unroll
    for (int nj = 0; nj < 4; ++nj) r[4 + nj] = *(const bf16x8*)(Bb + nj * 512);
  };

  bf16x8 ra[8], rb[8];
  stage(0); stage(1); stage(2);
  asm volatile("s_waitcnt vmcnt(6)" ::: "memory");
  __builtin_amdgcn_s_barrier();
  rdfrag(0, ra);

  auto body = [&](int kt, bf16x8 (&cur)[8], bf16x8 (&nxt)[8]) {
    if (kt + 3 < nkt) {
      stage(kt + 3);
      asm volatile("s_waitcnt vmcnt(6)" ::: "memory");
    } else if (kt + 2 < nkt) {
      asm volatile("s_waitcnt vmcnt(3)" ::: "memory");
    } else if (kt + 1 < nkt) {
      asm volatile("s_waitcnt vmcnt(0)" ::: "memory");
    }
    if (kt + 1 < nkt) {
      __builtin_amdgcn_s_barrier();
      rdfrag(kt + 1, nxt);
    }
    __builtin_amdgcn_s_setprio(1);
#pragma unroll
    for (int mi = 0; mi < 4; ++mi)
#pragma unroll
      for (int nj = 0; nj < 4; ++nj)
        acc[mi][nj] = __builtin_amdgcn_mfma_f32_16x16x32_bf16(cur[mi], cur[4 + nj], acc[mi][nj], 0, 0, 0);
    __builtin_amdgcn_s_setprio(0);
    if (kt + 1 < nkt) __builtin_amdgcn_s_barrier();
  };

#pragma unroll 1
  for (int kt = 0; kt < nkt; kt += 2) {
    body(kt, ra, rb);
    body(kt + 1, rb, ra);
  }
}

// ---------------------------------------------------------------------------
// core4h (score/pv): 256 thr / 128x128 tile, 4 waves (2M x 2N), per-wave
// 64x64 (acc[4][4]). BK=32; 3 LDS buffers of 16 KiB = 48 KiB -> 3 blocks/CU.
// Depth-2 prefetch: stage(kt+2) in body, gate vmcnt(4) certifies tile kt+1.
// Reg-dbuf fragments; 2 barriers/K-tile. WAR ledger: stage(kt+2) overwrites
// buf[(kt-1)%3], whose rdfrag(kt-1) reads were consumed by MFMA at iter kt-1
// before its trailing barrier. nkt even >= 2.
// ---------------------------------------------------------------------------
__device__ __forceinline__ void core4h(
    const unsigned short* __restrict__ A, long long lda,
    const unsigned short* __restrict__ B, long long ldb,
    int nkt, f32x4 (&acc)[4][4], unsigned short* lds) {
  const int tid  = threadIdx.x;          // 0..255
  const int lane = tid & 63;
  const int w    = tid >> 6;             // 0..3
  const int wm   = (w & 1) << 6;         // M half
  const int wn   = (w >> 1) << 6;        // N half
  const int fr   = lane & 15;
  const int fq   = lane >> 4;
  const int csel = (fq ^ ((fr >> 1) & 3)) << 3;
  const int srow = tid >> 2;             // 0..63
  const int scsw = ((tid & 3) ^ ((srow >> 1) & 3)) << 3;
  const unsigned short* Asrc0 = A + (long long)srow * lda + scsw;
  const unsigned short* Asrc1 = A + (long long)(srow + 64) * lda + scsw;
  const unsigned short* Bsrc0 = B + (long long)srow * ldb + scsw;
  const unsigned short* Bsrc1 = B + (long long)(srow + 64) * ldb + scsw;
  unsigned short* dsta = lds + tid * 8;  // 16B per thread per instr

  auto stage = [&](int kt) {
    const int bo = (kt % 3) * 8192;
    const long long ko = (long long)kt * 32;
    __builtin_amdgcn_global_load_lds(AS1(Asrc0 + ko), AS3(dsta + bo),        16, 0, 0);
    __builtin_amdgcn_global_load_lds(AS1(Asrc1 + ko), AS3(dsta + bo + 2048), 16, 0, 0);
    __builtin_amdgcn_global_load_lds(AS1(Bsrc0 + ko), AS3(dsta + bo + 4096), 16, 0, 0);
    __builtin_amdgcn_global_load_lds(AS1(Bsrc1 + ko), AS3(dsta + bo + 6144), 16, 0, 0);
  };
  auto rdfrag = [&](int kt, bf16x8 (&r)[8]) {
    const unsigned short* Ab = lds + (kt % 3) * 8192 + (wm + fr) * 32 + csel;
    const unsigned short* Bb = lds + (kt % 3) * 8192 + 4096 + (wn + fr) * 32 + csel;
#pragma unroll
    for (int mi = 0; mi < 4; ++mi) r[mi] = *(const bf16x8*)(Ab + mi * 512);
#pragma unroll
    for (int nj = 0; nj < 4; ++nj) r[4 + nj] = *(const bf16x8*)(Bb + nj * 512);
  };

  bf16x8 ra[8], rb[8];
  stage(0); stage(1);
  asm volatile("s_waitcnt vmcnt(4)" ::: "memory");   // tile 0 landed
  __builtin_amdgcn_s_barrier();
  rdfrag(0, ra);

  auto body = [&](int kt, bf16x8 (&cur)[8], bf16x8 (&nxt)[8]) {
    if (kt + 2 < nkt) {
      stage(kt + 2);
      asm volatile("s_waitcnt vmcnt(4)" ::: "memory");   // tile kt+1 landed
    } else if (kt + 1 < nkt) {
      asm volatile("s_waitcnt vmcnt(0)" ::: "memory");
    }
    if (kt + 1 < nkt) {
      __builtin_amdgcn_s_barrier();
      rdfrag(kt + 1, nxt);
    }
    __builtin_amdgcn_s_setprio(1);
#pragma unroll
    for (int mi = 0; mi < 4; ++mi)
#pragma unroll
      for (int nj = 0; nj < 4; ++nj)
        acc[mi][nj] = __builtin_amdgcn_mfma_f32_16x16x32_bf16(cur[mi], cur[4 + nj], acc[mi][nj], 0, 0, 0);
    __builtin_amdgcn_s_setprio(0);
    if (kt + 1 < nkt) __builtin_amdgcn_s_barrier();
  };

#pragma unroll 1
  for (int kt = 0; kt < nkt; kt += 2) {
    body(kt, ra, rb);
    body(kt + 1, rb, ra);
  }
}

// ---- Q/K/V projections; Q/K get RoPE; V computed AS Vt (swapped operands) -
// `which` is a kernel ARG (3 launches, grid (64,4) each).
__global__ __launch_bounds__(512, 2) void proj_rope(
    const unsigned short* __restrict__ xb,
    const unsigned short* __restrict__ Wq, const unsigned short* __restrict__ Wk,
    const unsigned short* __restrict__ Wv,
    const float* __restrict__ bq, const float* __restrict__ bk, const float* __restrict__ bv,
    unsigned short* __restrict__ Q, unsigned short* __restrict__ Ko,
    unsigned short* __restrict__ Vt, const int which) {
  __shared__ unsigned short lds[49152];   // 96 KiB: GEMM 4-buf, then repack
  const int tid = threadIdx.x, lane = tid & 63, w = tid >> 6;
  const int wr = w >> 2, wc = w & 3;
  const int cl = lane & 15, q4 = lane >> 4;

  f32x4 acc[4][4];
#pragma unroll
  for (int i = 0; i < 4; i++)
#pragma unroll
    for (int j = 0; j < 4; j++)
#pragma unroll
      for (int k = 0; k < 4; k++) acc[i][j][k] = 0.0f;

  if (which == 2) {
    // ---- V path: Vt[d,s] = sum_k Wv[d,k] x[s,k]; A = Wv (m=d), B = x (n=s)
    const int p = blockIdx.x + 64 * blockIdx.y;     // physical 0..255
    const int m0 = ((p >> 3) & 7) * 128;            // d tile
    const int n0 = (4 * (p & 7) + (p >> 6)) * 256;  // global s tile (XCD remap)
    core4(Wv + (long long)m0 * 1024, 1024, xb + (long long)n0 * 1024, 1024, 32, acc, lds);
    __syncthreads();
    const int b = n0 >> 11, sloc = n0 & 2047;
#pragma unroll
    for (int mi = 0; mi < 4; ++mi) {
      const int lr = wr * 64 + mi * 16 + q4 * 4;
#pragma unroll
      for (int rr = 0; rr < 4; ++rr) {
        const float b_ = bv[m0 + lr + rr];          // bias per d-row
#pragma unroll
        for (int nj = 0; nj < 4; ++nj)
          lds[(lr + rr) * 264 + wc * 64 + nj * 16 + cl] = f2bf(acc[mi][nj][rr] + b_);
      }
    }
    __syncthreads();
    unsigned short* Outb = Vt + (long long)b * 1024 * 2048;
#pragma unroll
    for (int it = 0; it < 8; ++it) {
      int c = it * 512 + tid;
      int row = c >> 5, c8 = (c & 31) << 3;
      bf16x8 v = *(const bf16x8*)(lds + row * 264 + c8);
      *(bf16x8*)(Outb + (long long)(m0 + row) * 2048 + sloc + c8) = v;
    }
    return;
  }

  // ---- Q/K path: bias + RoPE (native sin/cos) ----
  const int m0 = blockIdx.x * 128;    // token rows
  const int n0 = blockIdx.y * 256;    // feature cols
  const unsigned short* W = which == 0 ? Wq : Wk;
  const float* bias = which == 0 ? bq : bk;
  unsigned short* Out = which == 0 ? Q : Ko;

  core4(xb + (long long)m0 * 1024, 1024, W + (long long)n0 * 1024, 1024, 32, acc, lds);
  __syncthreads();

  const float NEG_L2T_512 = -0.025952563239354392f;  // -log2(10000)/512
  const float INV2PI = 0.15915494309189535f;
  float freqn[4];
#pragma unroll
  for (int nj = 0; nj < 4; ++nj) {
    int gn = n0 + wc * 64 + nj * 16 + cl;
    freqn[nj] = exp2f(NEG_L2T_512 * (float)(gn >> 1));
  }
#pragma unroll
  for (int mi = 0; mi < 4; ++mi) {
    const int lr = wr * 64 + mi * 16 + q4 * 4;
    const int t0 = (m0 & 2047) + lr;   // batch-local time (tiles never straddle)
#pragma unroll
    for (int nj = 0; nj < 4; ++nj) {
      const int gn = n0 + wc * 64 + nj * 16 + cl;
      const float bi = bias[gn];
#pragma unroll
      for (int rr = 0; rr < 4; ++rr) {
        float v = acc[mi][nj][rr] + bi;
        float partner = __shfl_xor(v, 1, 64);
        float ang = (float)(t0 + rr) * freqn[nj];
        float rev = ang * INV2PI;
        rev = rev - floorf(rev);           // v_sin/v_cos domain
        float c_ = __builtin_amdgcn_cosf(rev);
        float s_ = __builtin_amdgcn_sinf(rev);
        v = v * c_ + ((gn & 1) ? partner : -partner) * s_;
        lds[(lr + rr) * 264 + wc * 64 + nj * 16 + cl] = f2bf(v);
      }
    }
  }
  __syncthreads();
#pragma unroll
  for (int it = 0; it < 8; ++it) {
    int c = it * 512 + tid;
    int row = c >> 5, c8 = (c & 31) << 3;
    bf16x8 v = *(const bf16x8*)(lds + row * 264 + c8);
    *(bf16x8*)(Out + (long long)(m0 + row) * 1024 + n0 + c8) = v;
  }
}

// ---- P = exp(Q K^T / sqrt(C)) (causal-zeroed), bf16; row sums via atomics -
// Flat 544-block grid, XCD-chunked bijective remap (544 = 8*68).
__global__ __launch_bounds__(256, 2) void score_exp(const unsigned short* __restrict__ Q,
                                                    const unsigned short* __restrict__ Kk,
                                                    unsigned short* __restrict__ P,
                                                    float* __restrict__ row_sum) {
  __shared__ unsigned short sh[24576];   // 48 KiB: 3 GEMM bufs, then repack
  const int flat = blockIdx.x;                       // 0..543
  const int swz = (flat & 7) * 68 + (flat >> 3);     // bijective XCD chunking
  const int b = swz / 136;
  const int bx = swz % 136;
  int i = (int)((sqrtf(8.0f * (float)bx + 1.0f) - 1.0f) * 0.5f);
  while ((i + 1) * (i + 2) / 2 <= bx) ++i;
  while (i * (i + 1) / 2 > bx) --i;
  const int j = bx - i * (i + 1) / 2;       // 0..i
  const int m0 = i * 128, n0 = j * 128;
  const unsigned short* Qb = Q + (long long)b * 2048 * 1024;
  const unsigned short* Kb = Kk + (long long)b * 2048 * 1024;
  unsigned short* Pb = P + (long long)b * 2048 * 2048;
  float* rs = row_sum + b * 2048;

  f32x4 acc[4][4];
#pragma unroll
  for (int ii = 0; ii < 4; ii++)
#pragma unroll
    for (int jj = 0; jj < 4; jj++)
#pragma unroll
      for (int k = 0; k < 4; k++) acc[ii][jj][k] = 0.0f;

  core4h(Qb + (long long)m0 * 1024, 1024, Kb + (long long)n0 * 1024, 1024, 32, acc, sh);
  __syncthreads();

  const int tid = threadIdx.x, lane = tid & 63, w = tid >> 6;
  const int wm = (w & 1) << 6, wn = (w >> 1) << 6;
  const int cl = lane & 15, q4 = lane >> 4;
  const bool diag = (i == j);
#pragma unroll
  for (int mi = 0; mi < 4; mi++) {
    unsigned short vals[4][4];
    float rsum[4] = {0.f, 0.f, 0.f, 0.f};
#pragma unroll
    for (int ni = 0; ni < 4; ni++) {
      const int gn = n0 + wn + ni * 16 + cl;
#pragma unroll
      for (int rr = 0; rr < 4; rr++) {
        const int gm = m0 + wm + mi * 16 + q4 * 4 + rr;
        float e = (diag && gn > gm) ? 0.0f : __expf(acc[mi][ni][rr] * 0.03125f);
        vals[ni][rr] = f2bf(e);
        rsum[rr] += e;
      }
    }
#pragma unroll
    for (int rr = 0; rr < 4; rr++) {
#pragma unroll
      for (int off = 1; off < 16; off <<= 1) rsum[rr] += __shfl_xor(rsum[rr], off, 64);
    }
    if (cl == 0) {
      const int gm = m0 + wm + mi * 16 + q4 * 4;
#pragma unroll
      for (int rr = 0; rr < 4; rr++) atomicAdd(&rs[gm + rr], rsum[rr]);
    }
    repack_store_mi(vals, sh, mi, m0, n0, 2048, Pb);
  }
}

// ---- O = (P V) / row_sum -------------------------------------------------
// R17: flat 512-block grid, XCD-paired balanced decode. xcd = p&7 gets
// groups (b, mt=15-xcd) then (b, mt=xcd): per-CU work = one long + one
// short block = exactly 68 K-tiles; the 8 d-tiles of each (b,mt) group are
// contiguous on one XCD -> P panel L2-resident (8x reuse).
__global__ __launch_bounds__(256, 2) void pv_gemm(const unsigned short* __restrict__ P,
                                                  const unsigned short* __restrict__ Vt,
                                                  const float* __restrict__ row_sum,
                                                  unsigned short* __restrict__ O) {
  __shared__ unsigned short sh[24576];   // 48 KiB: 3 GEMM bufs, then repack
  const int p = blockIdx.x;          // 0..511
  const int xcd = p & 7;
  const int idx = p >> 3;            // 0..63
  const int g = idx >> 3;            // 0..7 (4 long groups, then 4 short)
  const int dt = idx & 7;            // d tile
  const int b  = (g < 4) ? g : g - 4;
  const int mt = (g < 4) ? 15 - xcd : xcd;
  const int m0 = mt * 128;           // t tile
  const int n0 = dt * 128;           // d tile
  const unsigned short* Pb = P + (long long)b * 2048 * 2048;
  const unsigned short* Vb = Vt + (long long)b * 1024 * 2048;
  const float* rs = row_sum + b * 2048;
  const int nkt = 4 * (mt + 1);      // K = m0+128 -> K/32, even >= 4

  f32x4 acc[4][4];
#pragma unroll
  for (int i = 0; i < 4; i++)
#pragma unroll
    for (int j = 0; j < 4; j++)
#pragma unroll
      for (int k = 0; k < 4; k++) acc[i][j][k] = 0.0f;

  core4h(Pb + (long long)m0 * 2048, 2048, Vb + (long long)n0 * 2048, 2048, nkt, acc, sh);
  __syncthreads();

  const int tid = threadIdx.x, lane = tid & 63, w = tid >> 6;
  const int wm = (w & 1) << 6;
  const int q4 = lane >> 4;
#pragma unroll
  for (int mi = 0; mi < 4; mi++) {
    unsigned short vals[4][4];
    float inv[4];
    const int gm0 = m0 + wm + mi * 16 + q4 * 4;
#pragma unroll
    for (int rr = 0; rr < 4; rr++) inv[rr] = 1.0f / rs[gm0 + rr];
#pragma unroll
    for (int ni = 0; ni < 4; ni++)
#pragma unroll
      for (int rr = 0; rr < 4; rr++)
        vals[ni][rr] = f2bf(acc[mi][ni][rr] * inv[rr]);
    repack_store_mi(vals, sh, mi, m0, n0, 1024, O + (long long)b * 2048 * 1024);
  }
}

// ---- out = O Wf^T + bf, fp32 out (core4, 512 thr) -------------------------
__global__ __launch_bounds__(512, 2) void final_gemm(const unsigned short* __restrict__ O,
                                                     const unsigned short* __restrict__ Wf,
                                                     const float* __restrict__ bf_,
                                                     float* __restrict__ out) {
  __shared__ unsigned short lds[49152];
  float* shf = (float*)lds;
  const int tid = threadIdx.x, lane = tid & 63, w = tid >> 6;
  const int wr = w >> 2, wc = w & 3;
  const int cl = lane & 15, q4 = lane >> 4;
  const int m0 = blockIdx.x * 128;
  const int n0 = blockIdx.y * 256;

  f32x4 acc[4][4];
#pragma unroll
  for (int i = 0; i < 4; i++)
#pragma unroll
    for (int j = 0; j < 4; j++)
#pragma unroll
      for (int k = 0; k < 4; k++) acc[i][j][k] = 0.0f;

  core4(O + (long long)m0 * 1024, 1024, Wf + (long long)n0 * 1024, 1024, 32, acc, lds);

  // fp32 repack in two 64-row rounds (64 x 260 floats = 66.5 KB <= 96 KB)
#pragma unroll
  for (int r = 0; r < 2; ++r) {
    __syncthreads();
    if (wr == r) {
#pragma unroll
      for (int mi = 0; mi < 4; ++mi)
#pragma unroll
        for (int nj = 0; nj < 4; ++nj) {
          const int col = wc * 64 + nj * 16 + cl;
          const float bi = bf_[n0 + col];
#pragma unroll
          for (int rr = 0; rr < 4; ++rr)
            shf[(mi * 16 + q4 * 4 + rr) * 260 + col] = acc[mi][nj][rr] + bi;
        }
    }
    __syncthreads();
#pragma unroll
    for (int it = 0; it < 8; ++it) {
      int c = it * 512 + tid;
      int row = c >> 6, c4 = (c & 63) << 2;
      float4 v = *(const float4*)(shf + row * 260 + c4);
      *(float4*)(out + (long long)(m0 + r * 64 + row) * 1024 + n0 + c4) = v;
    }
  }
}

// ---------------------------------------------------------------------------
extern "C" void kernel_launch(void* const* d_in, const int* in_sizes, int n_in,
                              void* d_out, int out_size, void* d_ws, size_t ws_size,
                              hipStream_t stream) {
  (void)in_sizes; (void)n_in; (void)out_size; (void)ws_size;
  const float* x   = (const float*)d_in[0];
  const float* Wq  = (const float*)d_in[1];
  const float* bq  = (const float*)d_in[2];
  const float* Wk  = (const float*)d_in[3];
  const float* bk  = (const float*)d_in[4];
  const float* Wv  = (const float*)d_in[5];
  const float* bv  = (const float*)d_in[6];
  const float* Wf  = (const float*)d_in[7];
  const float* bf_ = (const float*)d_in[8];
  float* out = (float*)d_out;

  char* ws = (char*)d_ws;
  const size_t MB = 1024 * 1024;
  unsigned short* xb  = (unsigned short*)(ws);             // 16 MB
  unsigned short* Wqb = (unsigned short*)(ws + 16 * MB);   // 2 MB
  unsigned short* Wkb = (unsigned short*)(ws + 18 * MB);   // 2 MB
  unsigned short* Wvb = (unsigned short*)(ws + 20 * MB);   // 2 MB
  unsigned short* Wfb = (unsigned short*)(ws + 22 * MB);   // 2 MB
  unsigned short* Qb  = (unsigned short*)(ws + 24 * MB);   // 16 MB
  unsigned short* Kb  = (unsigned short*)(ws + 40 * MB);   // 16 MB
  unsigned short* Vtb = (unsigned short*)(ws + 56 * MB);   // 16 MB
  unsigned short* Ob  = (unsigned short*)(ws + 72 * MB);   // 16 MB
  unsigned short* Pb  = (unsigned short*)(ws + 88 * MB);   // 32 MB P bf16
  float*          rsum= (float*)(ws + 120 * MB);           // 32 KB row sums

  cast_all<<<dim3(3145728 / 256), dim3(256), 0, stream>>>(x, Wq, Wk, Wv, Wf, xb, Wqb, Wkb, Wvb, Wfb, rsum);
  proj_rope<<<dim3(64, 4), dim3(512), 0, stream>>>(xb, Wqb, Wkb, Wvb, bq, bk, bv, Qb, Kb, Vtb, 0);
  proj_rope<<<dim3(64, 4), dim3(512), 0, stream>>>(xb, Wqb, Wkb, Wvb, bq, bk, bv, Qb, Kb, Vtb, 1);
  proj_rope<<<dim3(64, 4), dim3(512), 0, stream>>>(xb, Wqb, Wkb, Wvb, bq, bk, bv, Qb, Kb, Vtb, 2);
  score_exp<<<dim3(544), dim3(256), 0, stream>>>(Qb, Kb, Pb, rsum);
  pv_gemm<<<dim3(512), dim3(256), 0, stream>>>(Pb, Vtb, rsum, Ob);
  final_gemm<<<dim3(64, 4), dim3(512), 0, stream>>>(Ob, Wfb, bf_, out);
}